// Round 1
// baseline (534.240 us; speedup 1.0000x reference)
//
#include <hip/hip_runtime.h>
#include <cstdint>
#include <cstddef>

#define DEVI __device__ __forceinline__

typedef __bf16 bf16x8 __attribute__((ext_vector_type(8)));
typedef float f32x4 __attribute__((ext_vector_type(4)));

// ---------- scalar helpers ----------
DEVI ushort f2bf(float f) {
  union { float f; uint32_t u; } v; v.f = f;
  uint32_t u = v.u;
  uint32_t r = (u + 0x7FFFu + ((u >> 16) & 1u)) >> 16;  // RNE
  return (ushort)r;
}
DEVI float bf2f(ushort h) {
  union { uint32_t u; float f; } v; v.u = ((uint32_t)h) << 16;
  return v.f;
}

// async global->LDS, 16B per lane. LDS dest must be the wave-uniform base;
// HW adds lane*16. (CK-style integer-reinterpret casts to pick addrspaces.)
DEVI void async_copy16(const void* g, void* l) {
  __attribute__((address_space(1))) void* gp =
      reinterpret_cast<__attribute__((address_space(1))) void*>(
          reinterpret_cast<uintptr_t>(const_cast<void*>(g)));
  __attribute__((address_space(3))) void* lp =
      reinterpret_cast<__attribute__((address_space(3))) void*>(
          static_cast<uint32_t>(reinterpret_cast<uintptr_t>(l)));
  __builtin_amdgcn_global_load_lds(gp, lp, 16, 0, 0);
}

// ---------- f32 -> bf16 conversion ----------
__global__ void cvt_kernel(const float4* __restrict__ in, ushort4* __restrict__ out, int n4) {
  int i = blockIdx.x * blockDim.x + threadIdx.x;
  int stride = gridDim.x * blockDim.x;
  for (; i < n4; i += stride) {
    float4 f = in[i];
    ushort4 o;
    o.x = f2bf(f.x); o.y = f2bf(f.y); o.z = f2bf(f.z); o.w = f2bf(f.w);
    out[i] = o;
  }
}

__global__ void zero_kernel(float* __restrict__ p) { p[threadIdx.x] = 0.0f; }

// ---------- GEMM: C = A * B^T + bias ----------
// A: M x K bf16. If GATHER: A row r = [Ag[up[r]] (dg cols) | Ad[r] (K-dg cols)].
// B: N x K bf16 (torch Linear weight layout). 128x128 tile, BK=64, 4 waves (2x2),
// each wave 64x64 out = 4x4 frags of 16x16x32 MFMA, f32 accum.
// EPI 0: write bf16; EPI 1: write f32.
template <bool GATHER, int EPI>
__global__ __launch_bounds__(256, 2) void gemm_bt(
    const ushort* __restrict__ Ag, const ushort* __restrict__ Ad,
    const int* __restrict__ up, int dg,
    const ushort* __restrict__ B, const float* __restrict__ bias,
    void* __restrict__ Cout, int M, int N, int K) {
  constexpr int BK = 64;
  __shared__ ushort lA[128 * BK];
  __shared__ ushort lB[128 * BK];
  __shared__ int s_up[128];

  const int nbn = N >> 7;
  const int bm = (int)blockIdx.x / nbn;
  const int bn = (int)blockIdx.x % nbn;
  const int row0 = bm << 7, col0 = bn << 7;

  const int tid = threadIdx.x;
  const int lane = tid & 63;
  const int wave = tid >> 6;
  const int wm = wave >> 1, wn = wave & 1;

  if constexpr (GATHER) {
    if (tid < 128) s_up[tid] = up[row0 + tid];
    __syncthreads();
  }

  f32x4 acc[4][4] = {};
  const int dd = K - dg;

  for (int k0 = 0; k0 < K; k0 += BK) {
    // stage A tile (128 x 64 bf16 = 16KB), 4 x 16B per thread
#pragma unroll
    for (int it = 0; it < 4; ++it) {
      const int chunk = it * 256 + tid;
      const int r = chunk >> 3;
      const int c = (chunk & 7) << 3;
      const ushort* src;
      if constexpr (GATHER) {
        if (k0 < dg)
          src = Ag + (size_t)s_up[r] * dg + (k0 + c);
        else
          src = Ad + (size_t)(row0 + r) * dd + (k0 - dg + c);
      } else {
        src = Ag + (size_t)(row0 + r) * K + (k0 + c);
      }
      async_copy16(src, &lA[(size_t)(it * 256 + wave * 64) * 8]);
    }
    // stage B tile
#pragma unroll
    for (int it = 0; it < 4; ++it) {
      const int chunk = it * 256 + tid;
      const int r = chunk >> 3;
      const int c = (chunk & 7) << 3;
      async_copy16(B + (size_t)(col0 + r) * K + (k0 + c),
                   &lB[(size_t)(it * 256 + wave * 64) * 8]);
    }
    __syncthreads();
#pragma unroll
    for (int kk = 0; kk < 2; ++kk) {
      bf16x8 af[4], bfr[4];
#pragma unroll
      for (int m = 0; m < 4; ++m)
        af[m] = *(const bf16x8*)&lA[(wm * 64 + m * 16 + (lane & 15)) * BK + kk * 32 + (lane >> 4) * 8];
#pragma unroll
      for (int n = 0; n < 4; ++n)
        bfr[n] = *(const bf16x8*)&lB[(wn * 64 + n * 16 + (lane & 15)) * BK + kk * 32 + (lane >> 4) * 8];
#pragma unroll
      for (int m = 0; m < 4; ++m)
#pragma unroll
        for (int n = 0; n < 4; ++n)
          acc[m][n] = __builtin_amdgcn_mfma_f32_16x16x32_bf16(af[m], bfr[n], acc[m][n], 0, 0, 0);
    }
    __syncthreads();
  }

  // epilogue: D mapping col=lane&15, row=(lane>>4)*4+reg (m89-verified)
  const int cr = (lane >> 4) << 2;
  const int cc = lane & 15;
#pragma unroll
  for (int n = 0; n < 4; ++n) {
    const int colg = col0 + wn * 64 + n * 16 + cc;
    const float bv = bias[colg];
#pragma unroll
    for (int m = 0; m < 4; ++m) {
      const int rowg = row0 + wm * 64 + m * 16 + cr;
#pragma unroll
      for (int r = 0; r < 4; ++r) {
        const float v = acc[m][n][r] + bv;
        if constexpr (EPI == 0)
          ((ushort*)Cout)[(size_t)(rowg + r) * N + colg] = f2bf(v);
        else
          ((float*)Cout)[(size_t)(rowg + r) * N + colg] = v;
      }
    }
  }
}

// ---------- GroupNorm stats: per-group sum & sumsq over (C/32 ch x all rows) ----------
// x: Nrows x C bf16. stats: 32 groups x {sum, sumsq}.
__global__ void gn_stats(const ushort* __restrict__ x, int Nrows, int C,
                         float* __restrict__ stats) {
  __shared__ float ssum[32], ssq[32];
  const int tid = threadIdx.x;
  if (tid < 32) { ssum[tid] = 0.0f; ssq[tid] = 0.0f; }
  __syncthreads();
  const int tpr = C >> 2;          // threads per row (4 ch/thread)
  const int rpb = 256 / tpr;       // rows per block-iteration
  const int c4 = (tid % tpr) * 4;
  const int rl = tid / tpr;
  const int g = (c4 * 32) / C;     // 4 consecutive channels always one group
  float s = 0.0f, q = 0.0f;
  for (int r = blockIdx.x * rpb + rl; r < Nrows; r += gridDim.x * rpb) {
    ushort4 v = *(const ushort4*)&x[(size_t)r * C + c4];
    float f0 = bf2f(v.x), f1 = bf2f(v.y), f2 = bf2f(v.z), f3 = bf2f(v.w);
    s += f0 + f1 + f2 + f3;
    q += f0 * f0 + f1 * f1 + f2 * f2 + f3 * f3;
  }
  atomicAdd(&ssum[g], s);
  atomicAdd(&ssq[g], q);
  __syncthreads();
  if (tid < 32) {
    atomicAdd(&stats[tid * 2], ssum[tid]);
    atomicAdd(&stats[tid * 2 + 1], ssq[tid]);
  }
}

// ---------- GroupNorm apply + LeakyReLU(0.1), bf16 out ----------
__global__ void gn_apply(const ushort* __restrict__ x, const float* __restrict__ stats,
                         const float* __restrict__ gamma, const float* __restrict__ beta,
                         ushort* __restrict__ y, int Nrows, int C) {
  const int tid = threadIdx.x;
  const int tpr = C >> 2;
  const int rpb = 256 / tpr;
  const int c4 = (tid % tpr) * 4;
  const int rl = tid / tpr;
  const int g = (c4 * 32) / C;
  const float cnt = (float)Nrows * (float)(C / 32);
  const float mean = stats[g * 2] / cnt;
  const float var = stats[g * 2 + 1] / cnt - mean * mean;
  const float inv = rsqrtf(var + 1e-5f);
  float ga[4], be[4];
#pragma unroll
  for (int j = 0; j < 4; ++j) {
    const float gm = gamma[c4 + j] * inv;
    ga[j] = gm;
    be[j] = beta[c4 + j] - mean * gm;
  }
  for (int r = blockIdx.x * rpb + rl; r < Nrows; r += gridDim.x * rpb) {
    ushort4 v = *(const ushort4*)&x[(size_t)r * C + c4];
    float f[4] = { bf2f(v.x), bf2f(v.y), bf2f(v.z), bf2f(v.w) };
    ushort4 o;
#pragma unroll
    for (int j = 0; j < 4; ++j) {
      float t = f[j] * ga[j] + be[j];
      t = t > 0.0f ? t : 0.1f * t;
      ((ushort*)&o)[j] = f2bf(t);
    }
    *(ushort4*)&y[(size_t)r * C + c4] = o;
  }
}

// ---------- host ----------
static inline int imin(long a, long b) { return (int)(a < b ? a : b); }

extern "C" void kernel_launch(void* const* d_in, const int* in_sizes, int n_in,
                              void* d_out, int out_size, void* d_ws, size_t ws_size,
                              hipStream_t stream) {
  const float* s2   = (const float*)d_in[0];   // (131072, 256)
  const float* s3   = (const float*)d_in[1];   // (32768, 512)
  const float* s4   = (const float*)d_in[2];   // (8192, 1024)
  const float* s5   = (const float*)d_in[3];   // (2048, 2048)
  const int*   up1  = (const int*)d_in[4];     // (131072,)
  const int*   up2  = (const int*)d_in[5];     // (32768,)
  const int*   up3  = (const int*)d_in[6];     // (8192,)
  const float* W_in = (const float*)d_in[7];   // (2048, 2048)
  const float* b_in = (const float*)d_in[8];
  const float* W4   = (const float*)d_in[9];   // (1024, 3072)
  const float* b4   = (const float*)d_in[10];
  const float* g4   = (const float*)d_in[11];
  const float* be4  = (const float*)d_in[12];
  const float* W3   = (const float*)d_in[13];  // (512, 1536)
  const float* b3   = (const float*)d_in[14];
  const float* g3   = (const float*)d_in[15];
  const float* be3  = (const float*)d_in[16];
  const float* W2   = (const float*)d_in[17];  // (256, 768)
  const float* b2   = (const float*)d_in[18];
  float* out = (float*)d_out;
  char* ws = (char*)d_ws;

  // Workspace layout with liveness overlays (peak ~170 MB):
  ushort* s5b   = (ushort*)(ws + 0);           // 8.39 MB   dead after x5 GEMM
  ushort* Winb  = (ushort*)(ws + 8388608);     // 8.39 MB   dead after x5 GEMM
  ushort* x5b   = (ushort*)(ws + 16777216);    // 8.39 MB   dead after l4 GEMM
  ushort* W4b   = (ushort*)(ws + 25165824);    // 6.29 MB   dead after l4 GEMM
  ushort* l4lin = (ushort*)(ws + 0);           // 16.78 MB  over s5b+Winb
  ushort* l3lin = (ushort*)(ws + 0);           // 33.55 MB  over s5b..W4b (all dead)
  ushort* s4b   = (ushort*)(ws + 33554432);    // 16.78 MB  dead after l4 GEMM
  ushort* l4b   = (ushort*)(ws + 33554432);    // 16.78 MB  over s4b
  ushort* l3b   = (ushort*)(ws + 33554432);    // 33.55 MB  over l4b (dead after l3 GEMM)
  ushort* s3b   = (ushort*)(ws + 67108864);    // 33.55 MB  persistent
  ushort* s2b   = (ushort*)(ws + 100663296);   // 67.11 MB  persistent
  ushort* W3b   = (ushort*)(ws + 167772160);   // 1.57 MB
  ushort* W2b   = (ushort*)(ws + 169345024);   // 0.39 MB
  float*  stats = (float*)(ws + 169738240);    // 128 floats (2 layers x 32 groups x 2)

  zero_kernel<<<1, 128, 0, stream>>>(stats);

  auto cvt = [&](const float* src, ushort* dst, long n) {
    long n4 = n >> 2;
    int grid = imin((n4 + 255) / 256, 2048);
    cvt_kernel<<<grid, 256, 0, stream>>>((const float4*)src, (ushort4*)dst, (int)n4);
  };
  cvt(s5, s5b, 2048L * 2048);
  cvt(W_in, Winb, 2048L * 2048);
  cvt(W4, W4b, 1024L * 3072);
  cvt(W3, W3b, 512L * 1536);
  cvt(W2, W2b, 256L * 768);
  cvt(s4, s4b, 8192L * 1024);
  cvt(s3, s3b, 32768L * 512);
  cvt(s2, s2b, 131072L * 256);

  // x5 = s5 @ W_in^T + b_in -> bf16 (2048x2048)
  gemm_bt<false, 0><<<256, 256, 0, stream>>>(s5b, nullptr, nullptr, 0, Winb, b_in,
                                             x5b, 2048, 2048, 2048);
  // l4_lin = concat(x5[up3], s4) @ W4^T + b4 -> bf16 (8192x1024)
  gemm_bt<true, 0><<<512, 256, 0, stream>>>(x5b, s4b, up3, 2048, W4b, b4,
                                            l4lin, 8192, 1024, 3072);
  gn_stats<<<512, 256, 0, stream>>>(l4lin, 8192, 1024, stats);
  gn_apply<<<512, 256, 0, stream>>>(l4lin, stats, g4, be4, l4b, 8192, 1024);
  // l3_lin = concat(l4[up2], s3) @ W3^T + b3 -> bf16 (32768x512)
  gemm_bt<true, 0><<<1024, 256, 0, stream>>>(l4b, s3b, up2, 1024, W3b, b3,
                                             l3lin, 32768, 512, 1536);
  gn_stats<<<512, 256, 0, stream>>>(l3lin, 32768, 512, stats + 64);
  gn_apply<<<512, 256, 0, stream>>>(l3lin, stats + 64, g3, be3, l3b, 32768, 512);
  // out = concat(l3[up1], s2) @ W2^T + b2 -> f32 (131072x256)
  gemm_bt<true, 1><<<2048, 256, 0, stream>>>(l3b, s2b, up1, 512, W2b, b2,
                                             out, 131072, 256, 768);

  (void)in_sizes; (void)n_in; (void)out_size; (void)ws_size;
}

// Round 2
// 437.594 us; speedup vs baseline: 1.2209x; 1.2209x over previous
//
#include <hip/hip_runtime.h>
#include <cstdint>
#include <cstddef>

#define DEVI __device__ __forceinline__

typedef __bf16 bf16x8 __attribute__((ext_vector_type(8)));
typedef float f32x4 __attribute__((ext_vector_type(4)));

// ---------- scalar helpers ----------
DEVI ushort f2bf(float f) {
  union { float f; uint32_t u; } v; v.f = f;
  uint32_t u = v.u;
  uint32_t r = (u + 0x7FFFu + ((u >> 16) & 1u)) >> 16;  // RNE
  return (ushort)r;
}
DEVI float bf2f(ushort h) {
  union { uint32_t u; float f; } v; v.u = ((uint32_t)h) << 16;
  return v.f;
}

// async global->LDS, 16B per lane. LDS dest is wave-uniform base; HW adds lane*16.
DEVI void async_copy16(const void* g, void* l) {
  __attribute__((address_space(1))) void* gp =
      reinterpret_cast<__attribute__((address_space(1))) void*>(
          reinterpret_cast<uintptr_t>(const_cast<void*>(g)));
  __attribute__((address_space(3))) void* lp =
      reinterpret_cast<__attribute__((address_space(3))) void*>(
          static_cast<uint32_t>(reinterpret_cast<uintptr_t>(l)));
  __builtin_amdgcn_global_load_lds(gp, lp, 16, 0, 0);
}

// ---------- merged f32 -> bf16 conversion (8 segments, one launch) ----------
struct CvtSeg { const float4* src; ushort4* dst; };
struct CvtArgs { CvtSeg seg[8]; int start[9]; };

__global__ void cvt_multi(CvtArgs a, int total4) {
  int i = blockIdx.x * blockDim.x + threadIdx.x;
  const int stride = gridDim.x * blockDim.x;
  for (; i < total4; i += stride) {
    int s = 0;
#pragma unroll
    for (int j = 1; j < 8; ++j) s += (i >= a.start[j]);
    const int off = i - a.start[s];
    float4 f = a.seg[s].src[off];
    ushort4 o;
    o.x = f2bf(f.x); o.y = f2bf(f.y); o.z = f2bf(f.z); o.w = f2bf(f.w);
    a.seg[s].dst[off] = o;
  }
}

__global__ void zero_kernel(float* __restrict__ p) { p[threadIdx.x] = 0.0f; }

// ---------- 2-phase 128x128 GEMM (kept for x5 only) ----------
template <bool GATHER, int EPI>
__global__ __launch_bounds__(256, 2) void gemm_bt(
    const ushort* __restrict__ Ag, const ushort* __restrict__ Ad,
    const int* __restrict__ up, int dg,
    const ushort* __restrict__ B, const float* __restrict__ bias,
    void* __restrict__ Cout, int M, int N, int K) {
  constexpr int BK = 64;
  __shared__ ushort lA[128 * BK];
  __shared__ ushort lB[128 * BK];
  __shared__ int s_up[128];

  const int nbn = N >> 7;
  const int bm = (int)blockIdx.x / nbn;
  const int bn = (int)blockIdx.x % nbn;
  const int row0 = bm << 7, col0 = bn << 7;

  const int tid = threadIdx.x;
  const int lane = tid & 63;
  const int wave = tid >> 6;
  const int wm = wave >> 1, wn = wave & 1;

  if constexpr (GATHER) {
    if (tid < 128) s_up[tid] = up[row0 + tid];
    __syncthreads();
  }

  f32x4 acc[4][4] = {};
  const int dd = K - dg;

  for (int k0 = 0; k0 < K; k0 += BK) {
#pragma unroll
    for (int it = 0; it < 4; ++it) {
      const int chunk = it * 256 + tid;
      const int r = chunk >> 3;
      const int c = (chunk & 7) << 3;
      const ushort* src;
      if constexpr (GATHER) {
        if (k0 < dg)
          src = Ag + (size_t)s_up[r] * dg + (k0 + c);
        else
          src = Ad + (size_t)(row0 + r) * dd + (k0 - dg + c);
      } else {
        src = Ag + (size_t)(row0 + r) * K + (k0 + c);
      }
      async_copy16(src, &lA[(size_t)(it * 256 + wave * 64) * 8]);
    }
#pragma unroll
    for (int it = 0; it < 4; ++it) {
      const int chunk = it * 256 + tid;
      const int r = chunk >> 3;
      const int c = (chunk & 7) << 3;
      async_copy16(B + (size_t)(col0 + r) * K + (k0 + c),
                   &lB[(size_t)(it * 256 + wave * 64) * 8]);
    }
    __syncthreads();
#pragma unroll
    for (int kk = 0; kk < 2; ++kk) {
      bf16x8 af[4], bfr[4];
#pragma unroll
      for (int m = 0; m < 4; ++m)
        af[m] = *(const bf16x8*)&lA[(wm * 64 + m * 16 + (lane & 15)) * BK + kk * 32 + (lane >> 4) * 8];
#pragma unroll
      for (int n = 0; n < 4; ++n)
        bfr[n] = *(const bf16x8*)&lB[(wn * 64 + n * 16 + (lane & 15)) * BK + kk * 32 + (lane >> 4) * 8];
#pragma unroll
      for (int m = 0; m < 4; ++m)
#pragma unroll
        for (int n = 0; n < 4; ++n)
          acc[m][n] = __builtin_amdgcn_mfma_f32_16x16x32_bf16(af[m], bfr[n], acc[m][n], 0, 0, 0);
    }
    __syncthreads();
  }

  const int cr = (lane >> 4) << 2;
  const int cc = lane & 15;
#pragma unroll
  for (int n = 0; n < 4; ++n) {
    const int colg = col0 + wn * 64 + n * 16 + cc;
    const float bv = bias[colg];
#pragma unroll
    for (int m = 0; m < 4; ++m) {
      const int rowg = row0 + wm * 64 + m * 16 + cr;
#pragma unroll
      for (int r = 0; r < 4; ++r) {
        const float v = acc[m][n][r] + bv;
        if constexpr (EPI == 0)
          ((ushort*)Cout)[(size_t)(rowg + r) * N + colg] = f2bf(v);
        else
          ((float*)Cout)[(size_t)(rowg + r) * N + colg] = v;
      }
    }
  }
}

// ---------- 8-wave phased GEMM: BM=128, BN=256, BK=64, 3-buffer pipeline ----------
// C = A * B^T + bias. A: M x K (optionally gathered/concat), B: N x K.
// Schedule per K-tile: 2 phases (kk halves). Each phase: 8 ds_read_b128 +
// 3 global_load_lds (staging tile t+2 into buf (t+2)%3) + barrier + lgkmcnt(0)
// + setprio(1) + 16 MFMA + setprio(0) + barrier. Boundary: vmcnt(6) (counted,
// never 0 until tail) + barrier. Race-free: tile t+1 was fully issued during
// iter t-1, so vmcnt(6) with 6 newer loads outstanding implies t+1 landed.
// LDS T2 swizzle: 16B-chunk index ^= (row&7); applied on global SOURCE addr
// (global_load_lds writes linearly) and un-applied on ds_read.
template <bool GATHER, int EPI>
__global__ __launch_bounds__(512, 2) void gemm8(
    const ushort* __restrict__ Ag, const ushort* __restrict__ Ad,
    const int* __restrict__ up, int dg,
    const ushort* __restrict__ Bw, const float* __restrict__ bias,
    void* __restrict__ Cout, int M, int N, int K) {
  constexpr int BM = 128, BN = 256, BK = 64;
  constexpr int ABYTES = BM * BK * 2;      // 16 KB
  constexpr int BBYTES = BN * BK * 2;      // 32 KB
  constexpr int BUF = ABYTES + BBYTES;     // 48 KB
  __shared__ char smem[3 * BUF];           // 144 KB -> 1 block/CU
  __shared__ int s_up[BM];

  const int nbn = N / BN;
  const int bm = (int)blockIdx.x / nbn;
  const int bn = (int)blockIdx.x % nbn;
  const int row0 = bm * BM, col0 = bn * BN;

  const int tid = threadIdx.x;
  const int lane = tid & 63;
  const int wave = tid >> 6;
  const int wm = wave >> 2, wn = wave & 3;   // 2 M-waves x 4 N-waves
  const int dd = K - dg;

  if constexpr (GATHER) {
    if (tid < BM) s_up[tid] = up[row0 + tid];
  }
  __syncthreads();  // also drains all counters -> clean vmcnt baseline

  // --- precompute per-thread staging source pointers (swizzled) ---
  const ushort* pAg[2]; const ushort* pAd[2]; const ushort* pB[4];
#pragma unroll
  for (int li = 0; li < 2; ++li) {
    const int chunk = li * 512 + tid;
    const int r = chunk >> 3;
    const int colswz = ((chunk & 7) ^ (r & 7)) << 3;
    if constexpr (GATHER) {
      pAg[li] = Ag + (size_t)s_up[r] * dg + colswz;
      pAd[li] = Ad + (size_t)(row0 + r) * dd + colswz;
    } else {
      pAg[li] = Ag + (size_t)(row0 + r) * K + colswz;
      pAd[li] = nullptr;
    }
  }
#pragma unroll
  for (int li = 0; li < 4; ++li) {
    const int chunk = li * 512 + tid;
    const int r = chunk >> 3;
    const int colswz = ((chunk & 7) ^ (r & 7)) << 3;
    pB[li] = Bw + (size_t)(col0 + r) * K + colswz;
  }

  auto stageA = [&](int li, int k0, int bufb) {
    const ushort* s;
    if constexpr (GATHER) s = (k0 >= dg) ? (pAd[li] + (k0 - dg)) : (pAg[li] + k0);
    else s = pAg[li] + k0;
    async_copy16(s, &smem[bufb * BUF + li * 8192 + wave * 1024]);
  };
  auto stageB = [&](int li, int k0, int bufb) {
    async_copy16(pB[li] + k0, &smem[bufb * BUF + ABYTES + li * 8192 + wave * 1024]);
  };

  // --- precompute ds_read byte offsets (loop-invariant, swizzled) ---
  int offA[2][4], offB[2][4];
#pragma unroll
  for (int kk = 0; kk < 2; ++kk) {
#pragma unroll
    for (int m = 0; m < 4; ++m) {
      const int ch = kk * 4 + (lane >> 4);
      const int ra = wm * 64 + m * 16 + (lane & 15);
      offA[kk][m] = ra * 128 + ((ch ^ (ra & 7)) << 4);
      const int rb = wn * 64 + m * 16 + (lane & 15);
      offB[kk][m] = ABYTES + rb * 128 + ((ch ^ (rb & 7)) << 4);
    }
  }

  const int nt = K / BK;
  // --- prologue: stage tiles 0 and 1 (6 loads each, in order) ---
#pragma unroll
  for (int li = 0; li < 2; ++li) stageA(li, 0, 0);
#pragma unroll
  for (int li = 0; li < 4; ++li) stageB(li, 0, 0);
#pragma unroll
  for (int li = 0; li < 2; ++li) stageA(li, BK, 1);
#pragma unroll
  for (int li = 0; li < 4; ++li) stageB(li, BK, 1);
  asm volatile("s_waitcnt vmcnt(6)" ::: "memory");  // tile 0 landed
  __builtin_amdgcn_s_barrier();

  f32x4 acc[4][4] = {};
  int cb = 0;
  for (int t = 0; t < nt; ++t) {
    const int pb = (cb + 2 >= 3) ? cb - 1 : cb + 2;
    const bool pf = (t + 2) < nt;
    const int pk = (t + 2) * BK;
    const char* base = &smem[cb * BUF];
#pragma unroll
    for (int kk = 0; kk < 2; ++kk) {
      bf16x8 af[4], bv[4];
#pragma unroll
      for (int m = 0; m < 4; ++m) af[m] = *(const bf16x8*)(base + offA[kk][m]);
#pragma unroll
      for (int n = 0; n < 4; ++n) bv[n] = *(const bf16x8*)(base + offB[kk][n]);
      if (pf) {
        if (kk == 0) { stageA(0, pk, pb); stageA(1, pk, pb); stageB(0, pk, pb); }
        else         { stageB(1, pk, pb); stageB(2, pk, pb); stageB(3, pk, pb); }
      }
      __builtin_amdgcn_s_barrier();
      asm volatile("s_waitcnt lgkmcnt(0)" ::: "memory");
      __builtin_amdgcn_sched_barrier(0);
      __builtin_amdgcn_s_setprio(1);
#pragma unroll
      for (int m = 0; m < 4; ++m)
#pragma unroll
        for (int n = 0; n < 4; ++n)
          acc[m][n] = __builtin_amdgcn_mfma_f32_16x16x32_bf16(af[m], bv[n], acc[m][n], 0, 0, 0);
      __builtin_amdgcn_s_setprio(0);
      if (kk == 0) {
        __builtin_amdgcn_s_barrier();
      } else {
        if (pf) asm volatile("s_waitcnt vmcnt(6)" ::: "memory");  // tile t+1 landed
        else    asm volatile("s_waitcnt vmcnt(0)" ::: "memory");  // tail drain
        __builtin_amdgcn_s_barrier();
      }
    }
    cb = (cb + 1 >= 3) ? 0 : cb + 1;
  }

  // --- epilogue ---
  const int cr = (lane >> 4) << 2;
  const int cc = lane & 15;
#pragma unroll
  for (int n = 0; n < 4; ++n) {
    const int colg = col0 + wn * 64 + n * 16 + cc;
    const float bvv = bias[colg];
#pragma unroll
    for (int m = 0; m < 4; ++m) {
      const int rowg = row0 + wm * 64 + m * 16 + cr;
#pragma unroll
      for (int r2 = 0; r2 < 4; ++r2) {
        const float v = acc[m][n][r2] + bvv;
        if constexpr (EPI == 0)
          ((ushort*)Cout)[(size_t)(rowg + r2) * N + colg] = f2bf(v);
        else
          ((float*)Cout)[(size_t)(rowg + r2) * N + colg] = v;
      }
    }
  }
}

// ---------- GroupNorm stats ----------
__global__ void gn_stats(const ushort* __restrict__ x, int Nrows, int C,
                         float* __restrict__ stats) {
  __shared__ float ssum[32], ssq[32];
  const int tid = threadIdx.x;
  if (tid < 32) { ssum[tid] = 0.0f; ssq[tid] = 0.0f; }
  __syncthreads();
  const int tpr = C >> 2;
  const int rpb = 256 / tpr;
  const int c4 = (tid % tpr) * 4;
  const int rl = tid / tpr;
  const int g = (c4 * 32) / C;
  float s = 0.0f, q = 0.0f;
  for (int r = blockIdx.x * rpb + rl; r < Nrows; r += gridDim.x * rpb) {
    ushort4 v = *(const ushort4*)&x[(size_t)r * C + c4];
    float f0 = bf2f(v.x), f1 = bf2f(v.y), f2 = bf2f(v.z), f3 = bf2f(v.w);
    s += f0 + f1 + f2 + f3;
    q += f0 * f0 + f1 * f1 + f2 * f2 + f3 * f3;
  }
  atomicAdd(&ssum[g], s);
  atomicAdd(&ssq[g], q);
  __syncthreads();
  if (tid < 32) {
    atomicAdd(&stats[tid * 2], ssum[tid]);
    atomicAdd(&stats[tid * 2 + 1], ssq[tid]);
  }
}

// ---------- GroupNorm apply + LeakyReLU(0.1) ----------
__global__ void gn_apply(const ushort* __restrict__ x, const float* __restrict__ stats,
                         const float* __restrict__ gamma, const float* __restrict__ beta,
                         ushort* __restrict__ y, int Nrows, int C) {
  const int tid = threadIdx.x;
  const int tpr = C >> 2;
  const int rpb = 256 / tpr;
  const int c4 = (tid % tpr) * 4;
  const int rl = tid / tpr;
  const int g = (c4 * 32) / C;
  const float cnt = (float)Nrows * (float)(C / 32);
  const float mean = stats[g * 2] / cnt;
  const float var = stats[g * 2 + 1] / cnt - mean * mean;
  const float inv = rsqrtf(var + 1e-5f);
  float ga[4], be[4];
#pragma unroll
  for (int j = 0; j < 4; ++j) {
    const float gm = gamma[c4 + j] * inv;
    ga[j] = gm;
    be[j] = beta[c4 + j] - mean * gm;
  }
  for (int r = blockIdx.x * rpb + rl; r < Nrows; r += gridDim.x * rpb) {
    ushort4 v = *(const ushort4*)&x[(size_t)r * C + c4];
    float f[4] = { bf2f(v.x), bf2f(v.y), bf2f(v.z), bf2f(v.w) };
    ushort4 o;
#pragma unroll
    for (int j = 0; j < 4; ++j) {
      float t = f[j] * ga[j] + be[j];
      t = t > 0.0f ? t : 0.1f * t;
      ((ushort*)&o)[j] = f2bf(t);
    }
    *(ushort4*)&y[(size_t)r * C + c4] = o;
  }
}

// ---------- host ----------
static inline int imin(long a, long b) { return (int)(a < b ? a : b); }

extern "C" void kernel_launch(void* const* d_in, const int* in_sizes, int n_in,
                              void* d_out, int out_size, void* d_ws, size_t ws_size,
                              hipStream_t stream) {
  const float* s2   = (const float*)d_in[0];   // (131072, 256)
  const float* s3   = (const float*)d_in[1];   // (32768, 512)
  const float* s4   = (const float*)d_in[2];   // (8192, 1024)
  const float* s5   = (const float*)d_in[3];   // (2048, 2048)
  const int*   up1  = (const int*)d_in[4];
  const int*   up2  = (const int*)d_in[5];
  const int*   up3  = (const int*)d_in[6];
  const float* W_in = (const float*)d_in[7];   // (2048, 2048)
  const float* b_in = (const float*)d_in[8];
  const float* W4   = (const float*)d_in[9];   // (1024, 3072)
  const float* b4   = (const float*)d_in[10];
  const float* g4   = (const float*)d_in[11];
  const float* be4  = (const float*)d_in[12];
  const float* W3   = (const float*)d_in[13];  // (512, 1536)
  const float* b3   = (const float*)d_in[14];
  const float* g3   = (const float*)d_in[15];
  const float* be3  = (const float*)d_in[16];
  const float* W2   = (const float*)d_in[17];  // (256, 768)
  const float* b2   = (const float*)d_in[18];
  float* out = (float*)d_out;
  char* ws = (char*)d_ws;

  // Workspace layout (liveness overlays, peak ~170 MB)
  ushort* s5b   = (ushort*)(ws + 0);
  ushort* Winb  = (ushort*)(ws + 8388608);
  ushort* x5b   = (ushort*)(ws + 16777216);
  ushort* W4b   = (ushort*)(ws + 25165824);
  ushort* l4lin = (ushort*)(ws + 0);
  ushort* l3lin = (ushort*)(ws + 0);
  ushort* s4b   = (ushort*)(ws + 33554432);
  ushort* l4b   = (ushort*)(ws + 33554432);
  ushort* l3b   = (ushort*)(ws + 33554432);
  ushort* s3b   = (ushort*)(ws + 67108864);
  ushort* s2b   = (ushort*)(ws + 100663296);
  ushort* W3b   = (ushort*)(ws + 167772160);
  ushort* W2b   = (ushort*)(ws + 169345024);
  float*  stats = (float*)(ws + 169738240);

  zero_kernel<<<1, 128, 0, stream>>>(stats);

  // merged conversions (one launch)
  CvtArgs ca;
  const float* srcs[8] = { s5, W_in, W4, W3, W2, s4, s3, s2 };
  ushort* dsts[8] = { s5b, Winb, W4b, W3b, W2b, s4b, s3b, s2b };
  long ns[8] = { 2048L*2048, 2048L*2048, 1024L*3072, 512L*1536, 256L*768,
                 8192L*1024, 32768L*512, 131072L*256 };
  int cum = 0;
  for (int i = 0; i < 8; ++i) {
    ca.seg[i].src = (const float4*)srcs[i];
    ca.seg[i].dst = (ushort4*)dsts[i];
    ca.start[i] = cum;
    cum += (int)(ns[i] >> 2);
  }
  ca.start[8] = cum;
  cvt_multi<<<2048, 256, 0, stream>>>(ca, cum);

  // x5 = s5 @ W_in^T + b_in (2048x2048), old 2-phase kernel (grid 256)
  gemm_bt<false, 0><<<256, 256, 0, stream>>>(s5b, nullptr, nullptr, 0, Winb, b_in,
                                             x5b, 2048, 2048, 2048);
  // l4_lin = concat(x5[up3], s4) @ W4^T + b4  (8192x1024, K=3072) grid 64x4=256
  gemm8<true, 0><<<256, 512, 0, stream>>>(x5b, s4b, up3, 2048, W4b, b4,
                                          l4lin, 8192, 1024, 3072);
  gn_stats<<<512, 256, 0, stream>>>(l4lin, 8192, 1024, stats);
  gn_apply<<<512, 256, 0, stream>>>(l4lin, stats, g4, be4, l4b, 8192, 1024);
  // l3_lin = concat(l4[up2], s3) @ W3^T + b3  (32768x512, K=1536) grid 256x2=512
  gemm8<true, 0><<<512, 512, 0, stream>>>(l4b, s3b, up2, 1024, W3b, b3,
                                          l3lin, 32768, 512, 1536);
  gn_stats<<<512, 256, 0, stream>>>(l3lin, 32768, 512, stats + 64);
  gn_apply<<<512, 256, 0, stream>>>(l3lin, stats + 64, g3, be3, l3b, 32768, 512);
  // out = concat(l3[up1], s2) @ W2^T + b2  (131072x256, K=768) grid 1024x1
  gemm8<true, 1><<<1024, 512, 0, stream>>>(l3b, s2b, up1, 512, W2b, b2,
                                           out, 131072, 256, 768);

  (void)in_sizes; (void)n_in; (void)out_size; (void)ws_size;
}

// Round 3
// 415.531 us; speedup vs baseline: 1.2857x; 1.0531x over previous
//
#include <hip/hip_runtime.h>
#include <cstdint>
#include <cstddef>

#define DEVI __device__ __forceinline__
#define WAITVM(N) asm volatile("s_waitcnt vmcnt(" #N ")" ::: "memory")
#define WAITLGKM asm volatile("s_waitcnt lgkmcnt(0)" ::: "memory")

typedef __bf16 bf16x8 __attribute__((ext_vector_type(8)));
typedef float f32x4 __attribute__((ext_vector_type(4)));

// ---------- scalar helpers ----------
DEVI ushort f2bf(float f) {
  union { float f; uint32_t u; } v; v.f = f;
  uint32_t u = v.u;
  return (ushort)((u + 0x7FFFu + ((u >> 16) & 1u)) >> 16);  // RNE
}
DEVI float bf2f(ushort h) {
  union { uint32_t u; float f; } v; v.u = ((uint32_t)h) << 16;
  return v.f;
}
DEVI float lrelu(float t) { return t > 0.0f ? t : 0.1f * t; }

DEVI uint4 cvt8(float4 a, float4 b) {  // 8 f32 -> 8 packed bf16
  uint4 o;
  o.x = (uint32_t)f2bf(a.x) | ((uint32_t)f2bf(a.y) << 16);
  o.y = (uint32_t)f2bf(a.z) | ((uint32_t)f2bf(a.w) << 16);
  o.z = (uint32_t)f2bf(b.x) | ((uint32_t)f2bf(b.y) << 16);
  o.w = (uint32_t)f2bf(b.z) | ((uint32_t)f2bf(b.w) << 16);
  return o;
}
// GN+LeakyReLU on 8 packed bf16 with per-channel coefs
DEVI uint4 gn8(uint4 d, float4 g0, float4 g1, float4 b0, float4 b1) {
  float f0 = bf2f((ushort)(d.x & 0xffffu)), f1 = bf2f((ushort)(d.x >> 16));
  float f2 = bf2f((ushort)(d.y & 0xffffu)), f3 = bf2f((ushort)(d.y >> 16));
  float f4 = bf2f((ushort)(d.z & 0xffffu)), f5 = bf2f((ushort)(d.z >> 16));
  float f6 = bf2f((ushort)(d.w & 0xffffu)), f7 = bf2f((ushort)(d.w >> 16));
  float t0 = lrelu(f0 * g0.x + b0.x), t1 = lrelu(f1 * g0.y + b0.y);
  float t2 = lrelu(f2 * g0.z + b0.z), t3 = lrelu(f3 * g0.w + b0.w);
  float t4 = lrelu(f4 * g1.x + b1.x), t5 = lrelu(f5 * g1.y + b1.y);
  float t6 = lrelu(f6 * g1.z + b1.z), t7 = lrelu(f7 * g1.w + b1.w);
  uint4 o;
  o.x = (uint32_t)f2bf(t0) | ((uint32_t)f2bf(t1) << 16);
  o.y = (uint32_t)f2bf(t2) | ((uint32_t)f2bf(t3) << 16);
  o.z = (uint32_t)f2bf(t4) | ((uint32_t)f2bf(t5) << 16);
  o.w = (uint32_t)f2bf(t6) | ((uint32_t)f2bf(t7) << 16);
  return o;
}

// async global->LDS, 16B/lane; LDS dest is wave-uniform base.
DEVI void async_copy16(const void* g, void* l) {
  __attribute__((address_space(1))) void* gp =
      reinterpret_cast<__attribute__((address_space(1))) void*>(
          reinterpret_cast<uintptr_t>(const_cast<void*>(g)));
  __attribute__((address_space(3))) void* lp =
      reinterpret_cast<__attribute__((address_space(3))) void*>(
          static_cast<uint32_t>(reinterpret_cast<uintptr_t>(l)));
  __builtin_amdgcn_global_load_lds(gp, lp, 16, 0, 0);
}

// ---------- f32->bf16 conversion, weights+s5 only (5 segments, 8 elems/thread) ----------
struct CvtSeg { const float4* src; uint4* dst; };
struct CvtArgs { CvtSeg seg[5]; int start[6]; };

__global__ void cvt_multi(CvtArgs a, int total8) {
  int i = blockIdx.x * blockDim.x + threadIdx.x;
  const int stride = gridDim.x * blockDim.x;
  for (; i < total8; i += stride) {
    int s = 0;
#pragma unroll
    for (int j = 1; j < 5; ++j) s += (i >= a.start[j]);
    const int off = i - a.start[s];
    float4 f0 = a.seg[s].src[off * 2];
    float4 f1 = a.seg[s].src[off * 2 + 1];
    a.seg[s].dst[off] = cvt8(f0, f1);
  }
}

__global__ void zero_kernel(float* __restrict__ p) { p[threadIdx.x] = 0.0f; }

// ---------- GN coef: ga=gamma*rsqrt(var+eps), be=beta-mean*ga ----------
__global__ void gn_coef(const float* __restrict__ stats, const float* __restrict__ gamma,
                        const float* __restrict__ beta, float* __restrict__ ga,
                        float* __restrict__ be, int C, float invcnt) {
  int ch = blockIdx.x * blockDim.x + threadIdx.x;
  if (ch >= C) return;
  int g = ch / (C >> 5);
  float mean = stats[2 * g] * invcnt;
  float var = stats[2 * g + 1] * invcnt - mean * mean;
  float inv = rsqrtf(var + 1e-5f);
  float gm = gamma[ch] * inv;
  ga[ch] = gm;
  be[ch] = beta[ch] - mean * gm;
}

// ---------- 2-phase 128x128 GEMM (x5 only, bf16 in) ----------
template <int EPI>
__global__ __launch_bounds__(256, 2) void gemm_bt(
    const ushort* __restrict__ Ag, const ushort* __restrict__ B,
    const float* __restrict__ bias, void* __restrict__ Cout, int M, int N, int K) {
  constexpr int BK = 64;
  __shared__ ushort lA[128 * BK];
  __shared__ ushort lB[128 * BK];
  const int nbn = N >> 7;
  const int bm = (int)blockIdx.x / nbn;
  const int bn = (int)blockIdx.x % nbn;
  const int row0 = bm << 7, col0 = bn << 7;
  const int tid = threadIdx.x;
  const int lane = tid & 63;
  const int wave = tid >> 6;
  const int wm = wave >> 1, wn = wave & 1;

  f32x4 acc[4][4] = {};
  for (int k0 = 0; k0 < K; k0 += BK) {
#pragma unroll
    for (int it = 0; it < 4; ++it) {
      const int chunk = it * 256 + tid;
      const int r = chunk >> 3;
      const int c = (chunk & 7) << 3;
      async_copy16(Ag + (size_t)(row0 + r) * K + (k0 + c),
                   &lA[(size_t)(it * 256 + wave * 64) * 8]);
    }
#pragma unroll
    for (int it = 0; it < 4; ++it) {
      const int chunk = it * 256 + tid;
      const int r = chunk >> 3;
      const int c = (chunk & 7) << 3;
      async_copy16(B + (size_t)(col0 + r) * K + (k0 + c),
                   &lB[(size_t)(it * 256 + wave * 64) * 8]);
    }
    __syncthreads();
#pragma unroll
    for (int kk = 0; kk < 2; ++kk) {
      bf16x8 af[4], bfr[4];
#pragma unroll
      for (int m = 0; m < 4; ++m)
        af[m] = *(const bf16x8*)&lA[(wm * 64 + m * 16 + (lane & 15)) * BK + kk * 32 + (lane >> 4) * 8];
#pragma unroll
      for (int n = 0; n < 4; ++n)
        bfr[n] = *(const bf16x8*)&lB[(wn * 64 + n * 16 + (lane & 15)) * BK + kk * 32 + (lane >> 4) * 8];
#pragma unroll
      for (int m = 0; m < 4; ++m)
#pragma unroll
        for (int n = 0; n < 4; ++n)
          acc[m][n] = __builtin_amdgcn_mfma_f32_16x16x32_bf16(af[m], bfr[n], acc[m][n], 0, 0, 0);
    }
    __syncthreads();
  }
  const int cr = (lane >> 4) << 2;
  const int cc = lane & 15;
#pragma unroll
  for (int n = 0; n < 4; ++n) {
    const int colg = col0 + wn * 64 + n * 16 + cc;
    const float bv = bias[colg];
#pragma unroll
    for (int m = 0; m < 4; ++m) {
      const int rowg = row0 + wm * 64 + m * 16 + cr;
#pragma unroll
      for (int r = 0; r < 4; ++r) {
        const float v = acc[m][n][r] + bv;
        if constexpr (EPI == 0)
          ((ushort*)Cout)[(size_t)(rowg + r) * N + colg] = f2bf(v);
        else
          ((float*)Cout)[(size_t)(rowg + r) * N + colg] = v;
      }
    }
  }
}

// ---------- 8-wave phased GEMM with fused concat/gather, f32-direct cvt, GN-gather ----------
// C = A*B^T + bias. A row r = [ GATHERPART(up[r]) | DIRECT f32 feats row r ].
// GNG=0: gather part = plain bf16 via global_load_lds (pre-swizzled source).
// GNG=1: gather part = bf16 lin buffer, GN+LeakyReLU applied in-register at staging.
// Direct part: f32 source, reg-staged + RNE->bf16 + ds_write.
// EPI: 0=bf16 out, 1=f32 out. STATS: accumulate per-group (sum,sumsq) of outputs.
// Pipeline: 3 LDS buffers, BK=64, counted vmcnt (see round-2/3 notes).
template <int GNG, int EPI, int STATS>
__global__ __launch_bounds__(512, 2) void gemm8(
    const ushort* __restrict__ Ag, const float* __restrict__ Adf,
    const int* __restrict__ up, int dg,
    const float* __restrict__ gacoef, const float* __restrict__ becoef,
    const ushort* __restrict__ Bw, const float* __restrict__ bias,
    void* __restrict__ Cout, float* __restrict__ stats,
    int M, int N, int K) {
  constexpr int BM = 128, BN = 256, BK = 64;
  constexpr int ABY = BM * BK * 2;           // 16384
  constexpr int BUF = ABY + BN * BK * 2;     // 49152
  __shared__ __align__(16) char smem[3 * BUF];
  __shared__ int s_up[BM];
  __shared__ float ssum[32], ssq[32];

  const int nbn = N / BN;
  const int bm = (int)blockIdx.x / nbn;
  const int bn = (int)blockIdx.x % nbn;
  const int row0 = bm * BM, col0 = bn * BN;
  const int tid = threadIdx.x, lane = tid & 63, wave = tid >> 6;
  const int wm = wave >> 2, wn = wave & 3;   // 2 M-waves x 4 N-waves
  const int dd = K - dg;
  const int ng = dg / BK;
  const int nt = K / BK;

  if (tid < BM) s_up[tid] = up[row0 + tid];
  if constexpr (STATS) { if (tid < 32) { ssum[tid] = 0.f; ssq[tid] = 0.f; } }
  __syncthreads();   // drains all counters -> clean vmcnt baseline

  // per-thread staging geometry (swizzle: chunk col ^= row&7)
  int r_[2], cs_[2];
#pragma unroll
  for (int li = 0; li < 2; ++li) {
    const int chunk = li * 512 + tid;
    r_[li] = chunk >> 3;
    cs_[li] = ((chunk & 7) ^ (r_[li] & 7)) << 3;
  }
  const ushort* pG[2]; const float* pD[2];
#pragma unroll
  for (int li = 0; li < 2; ++li) {
    pG[li] = Ag + (size_t)s_up[r_[li]] * dg + cs_[li];
    pD[li] = Adf + (size_t)(row0 + r_[li]) * dd + cs_[li];
  }
  const ushort* pB[4];
#pragma unroll
  for (int li = 0; li < 4; ++li) {
    const int chunk = li * 512 + tid;
    const int rb = chunk >> 3;
    const int cw = ((chunk & 7) ^ (rb & 7)) << 3;
    pB[li] = Bw + (size_t)(col0 + rb) * K + cw;
  }

  // reg staging state
  float4 rd0, rd1, rd2, rd3;
  uint4 rg0, rg1;
  float4 ga0, ga1, ga2, ga3, be0, be1, be2, be3;

  auto issueA = [&](int t2, char* bufb) {
    const int k0 = t2 * BK;
    if (t2 < ng) {
      if constexpr (GNG == 0) {
        async_copy16(pG[0] + k0, bufb + 0 * 8192 + wave * 1024);
        async_copy16(pG[1] + k0, bufb + 1 * 8192 + wave * 1024);
      } else {
        rg0 = *(const uint4*)(pG[0] + k0);
        ga0 = *(const float4*)(gacoef + k0 + cs_[0]);
        ga1 = *(const float4*)(gacoef + k0 + cs_[0] + 4);
        be0 = *(const float4*)(becoef + k0 + cs_[0]);
        be1 = *(const float4*)(becoef + k0 + cs_[0] + 4);
        rg1 = *(const uint4*)(pG[1] + k0);
        ga2 = *(const float4*)(gacoef + k0 + cs_[1]);
        ga3 = *(const float4*)(gacoef + k0 + cs_[1] + 4);
        be2 = *(const float4*)(becoef + k0 + cs_[1]);
        be3 = *(const float4*)(becoef + k0 + cs_[1] + 4);
      }
    } else {
      const int kd = k0 - dg;
      rd0 = *(const float4*)(pD[0] + kd);
      rd1 = *(const float4*)(pD[0] + kd + 4);
      rd2 = *(const float4*)(pD[1] + kd);
      rd3 = *(const float4*)(pD[1] + kd + 4);
    }
  };
  auto consumeA = [&](int t1, char* bufb) {  // only for reg-type tiles
    if (t1 < ng) {  // GNG==1 gather
      *(uint4*)(bufb + 0 * 8192 + tid * 16) = gn8(rg0, ga0, ga1, be0, be1);
      *(uint4*)(bufb + 1 * 8192 + tid * 16) = gn8(rg1, ga2, ga3, be2, be3);
    } else {
      *(uint4*)(bufb + 0 * 8192 + tid * 16) = cvt8(rd0, rd1);
      *(uint4*)(bufb + 1 * 8192 + tid * 16) = cvt8(rd2, rd3);
    }
  };
  auto issueB = [&](int t2, char* bufb) {
#pragma unroll
    for (int li = 0; li < 4; ++li)
      async_copy16(pB[li] + t2 * BK, bufb + ABY + li * 8192 + wave * 1024);
  };

  // ds_read fragment offsets (loop-invariant, swizzled)
  int offA[2][4], offB[2][4];
#pragma unroll
  for (int kk = 0; kk < 2; ++kk) {
#pragma unroll
    for (int m = 0; m < 4; ++m) {
      const int ch = kk * 4 + (lane >> 4);
      const int ra = wm * 64 + m * 16 + (lane & 15);
      offA[kk][m] = ra * 128 + ((ch ^ (ra & 7)) << 4);
      const int rb = wn * 64 + m * 16 + (lane & 15);
      offB[kk][m] = ABY + rb * 128 + ((ch ^ (rb & 7)) << 4);
    }
  }

  // --- prologue: tile 0 staged, tile 1 issued ---
  issueA(0, smem); issueB(0, smem);
  if ((GNG == 1) && (0 < ng)) { WAITVM(4); consumeA(0, smem); }
  issueA(1, smem + BUF); issueB(1, smem + BUF);
  if (1 < ng) { if constexpr (GNG == 0) WAITVM(6); else WAITVM(14); }
  else WAITVM(8);   // retire tile-0 loads; tile-1 stays in flight

  f32x4 acc[4][4] = {};
  for (int t = 0; t < nt; ++t) {
    char* bufc  = smem + (t % 3) * BUF;
    char* bufn1 = smem + ((t + 1) % 3) * BUF;
    char* bufn2 = smem + ((t + 2) % 3) * BUF;
    // W1: consume A(t+1) regs (if reg-type)
    if (t + 1 < nt) {
      const bool reg1 = (GNG == 1) || (t + 1 >= ng);
      if (reg1) { WAITVM(4); consumeA(t + 1, bufn1); }
    }
    WAITLGKM;
    __builtin_amdgcn_s_barrier();          // entry: buf[t%3] ready
    // kk = 0
    {
      bf16x8 af[4], bv[4];
#pragma unroll
      for (int m = 0; m < 4; ++m) af[m] = *(const bf16x8*)(bufc + offA[0][m]);
#pragma unroll
      for (int n = 0; n < 4; ++n) bv[n] = *(const bf16x8*)(bufc + offB[0][n]);
      if (t + 2 < nt) issueA(t + 2, bufn2);
      WAITLGKM;
      __builtin_amdgcn_sched_barrier(0);
      __builtin_amdgcn_s_setprio(1);
#pragma unroll
      for (int m = 0; m < 4; ++m)
#pragma unroll
        for (int n = 0; n < 4; ++n)
          acc[m][n] = __builtin_amdgcn_mfma_f32_16x16x32_bf16(af[m], bv[n], acc[m][n], 0, 0, 0);
      __builtin_amdgcn_s_setprio(0);
      __builtin_amdgcn_s_barrier();        // mid
    }
    // kk = 1
    {
      bf16x8 af[4], bv[4];
#pragma unroll
      for (int m = 0; m < 4; ++m) af[m] = *(const bf16x8*)(bufc + offA[1][m]);
#pragma unroll
      for (int n = 0; n < 4; ++n) bv[n] = *(const bf16x8*)(bufc + offB[1][n]);
      if (t + 2 < nt) issueB(t + 2, bufn2);
      WAITLGKM;
      __builtin_amdgcn_sched_barrier(0);
      __builtin_amdgcn_s_setprio(1);
#pragma unroll
      for (int m = 0; m < 4; ++m)
#pragma unroll
        for (int n = 0; n < 4; ++n)
          acc[m][n] = __builtin_amdgcn_mfma_f32_16x16x32_bf16(af[m], bv[n], acc[m][n], 0, 0, 0);
      __builtin_amdgcn_s_setprio(0);
    }
    // W4: tile t+1 landed (counted; never 0 until tail)
    if (t + 2 >= nt) WAITVM(0);
    else if (t + 2 < ng) { if constexpr (GNG == 0) WAITVM(6); else WAITVM(14); }
    else WAITVM(8);
    __builtin_amdgcn_s_barrier();          // end
  }

  // --- epilogue: bias, store, optional group stats ---
  const int cr = (lane >> 4) << 2;
  const int cc = lane & 15;
  float sacc[4] = {0, 0, 0, 0}, qacc[4] = {0, 0, 0, 0};
#pragma unroll
  for (int n = 0; n < 4; ++n) {
    const int colg = col0 + wn * 64 + n * 16 + cc;
    const float bvv = bias[colg];
#pragma unroll
    for (int m = 0; m < 4; ++m) {
      const int rowg = row0 + wm * 64 + m * 16 + cr;
#pragma unroll
      for (int r2 = 0; r2 < 4; ++r2) {
        const float v = acc[m][n][r2] + bvv;
        if constexpr (STATS) { sacc[n] += v; qacc[n] += v * v; }
        if constexpr (EPI == 0)
          ((ushort*)Cout)[(size_t)(rowg + r2) * N + colg] = f2bf(v);
        else
          ((float*)Cout)[(size_t)(rowg + r2) * N + colg] = v;
      }
    }
  }
  if constexpr (STATS) {
    const int gsize = N >> 5;
#pragma unroll
    for (int n = 0; n < 4; ++n) {
      float s = sacc[n], q = qacc[n];
      s += __shfl_xor(s, 16); q += __shfl_xor(q, 16);
      s += __shfl_xor(s, 32); q += __shfl_xor(q, 32);
      if (lane < 16) {
        const int colg = col0 + wn * 64 + n * 16 + lane;
        const int g = colg / gsize;
        atomicAdd(&ssum[g], s);
        atomicAdd(&ssq[g], q);
      }
    }
    __syncthreads();
    if (tid < 32) {
      const int g0 = col0 / gsize, g1 = (col0 + BN) / gsize;
      if (tid >= g0 && tid < g1) {
        atomicAdd(&stats[2 * tid], ssum[tid]);
        atomicAdd(&stats[2 * tid + 1], ssq[tid]);
      }
    }
  }
}

// ---------- host ----------
extern "C" void kernel_launch(void* const* d_in, const int* in_sizes, int n_in,
                              void* d_out, int out_size, void* d_ws, size_t ws_size,
                              hipStream_t stream) {
  const float* s2   = (const float*)d_in[0];   // (131072, 256)
  const float* s3   = (const float*)d_in[1];   // (32768, 512)
  const float* s4   = (const float*)d_in[2];   // (8192, 1024)
  const float* s5   = (const float*)d_in[3];   // (2048, 2048)
  const int*   up1  = (const int*)d_in[4];
  const int*   up2  = (const int*)d_in[5];
  const int*   up3  = (const int*)d_in[6];
  const float* W_in = (const float*)d_in[7];   // (2048, 2048)
  const float* b_in = (const float*)d_in[8];
  const float* W4   = (const float*)d_in[9];   // (1024, 3072)
  const float* b4   = (const float*)d_in[10];
  const float* g4   = (const float*)d_in[11];
  const float* bt4  = (const float*)d_in[12];
  const float* W3   = (const float*)d_in[13];  // (512, 1536)
  const float* b3   = (const float*)d_in[14];
  const float* g3   = (const float*)d_in[15];
  const float* bt3  = (const float*)d_in[16];
  const float* W2   = (const float*)d_in[17];  // (256, 768)
  const float* b2   = (const float*)d_in[18];
  float* out = (float*)d_out;
  char* ws = (char*)d_ws;

  // Workspace (~84 MB)
  ushort* s5b   = (ushort*)(ws + 0);
  ushort* Winb  = (ushort*)(ws + 8388608);
  ushort* x5b   = (ushort*)(ws + 16777216);
  ushort* W4b   = (ushort*)(ws + 25165824);
  ushort* W3b   = (ushort*)(ws + 31457280);
  ushort* W2b   = (ushort*)(ws + 33030144);
  float*  stats = (float*)(ws + 33423360);   // 128 f32 (2 layers x 32 x 2)
  float*  cga4  = (float*)(ws + 33423872);
  float*  cbe4  = (float*)(ws + 33427968);
  float*  cga3  = (float*)(ws + 33432064);
  float*  cbe3  = (float*)(ws + 33434112);
  ushort* l4lin = (ushort*)(ws + 33554432);  // 8192x1024
  ushort* l3lin = (ushort*)(ws + 50331648);  // 32768x512

  zero_kernel<<<1, 128, 0, stream>>>(stats);

  // convert weights + s5 only
  CvtArgs ca;
  const float* srcs[5] = { s5, W_in, W4, W3, W2 };
  ushort* dsts[5] = { s5b, Winb, W4b, W3b, W2b };
  long ns[5] = { 2048L*2048, 2048L*2048, 1024L*3072, 512L*1536, 256L*768 };
  int cum = 0;
  for (int i = 0; i < 5; ++i) {
    ca.seg[i].src = (const float4*)srcs[i];
    ca.seg[i].dst = (uint4*)dsts[i];
    ca.start[i] = cum;
    cum += (int)(ns[i] >> 3);
  }
  ca.start[5] = cum;
  cvt_multi<<<2048, 256, 0, stream>>>(ca, cum);

  // x5 = s5 @ W_in^T + b_in (2048x2048)
  gemm_bt<0><<<256, 256, 0, stream>>>(s5b, Winb, b_in, x5b, 2048, 2048, 2048);
  // l4lin = concat(x5[up3], s4_f32) @ W4^T + b4, stats fused  (8192x1024, K=3072)
  gemm8<0, 0, 1><<<256, 512, 0, stream>>>(x5b, s4, up3, 2048, nullptr, nullptr,
                                          W4b, b4, l4lin, stats, 8192, 1024, 3072);
  gn_coef<<<4, 256, 0, stream>>>(stats, g4, bt4, cga4, cbe4, 1024, 1.0f / 262144.0f);
  // l3lin = concat(GN(l4lin)[up2], s3_f32) @ W3^T + b3, stats fused (32768x512, K=1536)
  gemm8<1, 0, 1><<<512, 512, 0, stream>>>(l4lin, s3, up2, 1024, cga4, cbe4,
                                          W3b, b3, l3lin, stats + 64, 32768, 512, 1536);
  gn_coef<<<2, 256, 0, stream>>>(stats + 64, g3, bt3, cga3, cbe3, 512, 1.0f / 524288.0f);
  // out = concat(GN(l3lin)[up1], s2_f32) @ W2^T + b2 -> f32 (131072x256, K=768)
  gemm8<1, 1, 0><<<1024, 512, 0, stream>>>(l3lin, s2, up1, 512, cga3, cbe3,
                                           W2b, b2, out, nullptr, 131072, 256, 768);

  (void)in_sizes; (void)n_in; (void)out_size; (void)ws_size;
}

// Round 5
// 403.785 us; speedup vs baseline: 1.3231x; 1.0291x over previous
//
#include <hip/hip_runtime.h>
#include <cstdint>
#include <cstddef>

#define DEVI __device__ __forceinline__
#define WAITVM0 asm volatile("s_waitcnt vmcnt(0)" ::: "memory")
#define WAITVM4 asm volatile("s_waitcnt vmcnt(4)" ::: "memory")
#define WAITLGKM asm volatile("s_waitcnt lgkmcnt(0)" ::: "memory")

typedef __bf16 bf16x8 __attribute__((ext_vector_type(8)));
typedef float f32x4 __attribute__((ext_vector_type(4)));
typedef uint32_t u32x4 __attribute__((ext_vector_type(4)));

// ---------- scalar helpers ----------
DEVI ushort f2bf(float f) {
  union { float f; uint32_t u; } v; v.f = f;
  uint32_t u = v.u;
  return (ushort)((u + 0x7FFFu + ((u >> 16) & 1u)) >> 16);  // RNE
}
DEVI float bf2f(ushort h) {
  union { uint32_t u; float f; } v; v.u = ((uint32_t)h) << 16;
  return v.f;
}
DEVI float lrelu(float t) { return t > 0.0f ? t : 0.1f * t; }

DEVI u32x4 cvt8(f32x4 a, f32x4 b) {  // 8 f32 -> 8 packed bf16
  u32x4 o;
  o[0] = (uint32_t)f2bf(a[0]) | ((uint32_t)f2bf(a[1]) << 16);
  o[1] = (uint32_t)f2bf(a[2]) | ((uint32_t)f2bf(a[3]) << 16);
  o[2] = (uint32_t)f2bf(b[0]) | ((uint32_t)f2bf(b[1]) << 16);
  o[3] = (uint32_t)f2bf(b[2]) | ((uint32_t)f2bf(b[3]) << 16);
  return o;
}
// GN+LeakyReLU on 8 packed bf16 with per-channel f32 coefs
DEVI u32x4 gn8(u32x4 d, f32x4 g0, f32x4 g1, f32x4 b0, f32x4 b1) {
  float f0 = bf2f((ushort)(d[0] & 0xffffu)), f1 = bf2f((ushort)(d[0] >> 16));
  float f2 = bf2f((ushort)(d[1] & 0xffffu)), f3 = bf2f((ushort)(d[1] >> 16));
  float f4 = bf2f((ushort)(d[2] & 0xffffu)), f5 = bf2f((ushort)(d[2] >> 16));
  float f6 = bf2f((ushort)(d[3] & 0xffffu)), f7 = bf2f((ushort)(d[3] >> 16));
  float t0 = lrelu(f0 * g0[0] + b0[0]), t1 = lrelu(f1 * g0[1] + b0[1]);
  float t2 = lrelu(f2 * g0[2] + b0[2]), t3 = lrelu(f3 * g0[3] + b0[3]);
  float t4 = lrelu(f4 * g1[0] + b1[0]), t5 = lrelu(f5 * g1[1] + b1[1]);
  float t6 = lrelu(f6 * g1[2] + b1[2]), t7 = lrelu(f7 * g1[3] + b1[3]);
  u32x4 o;
  o[0] = (uint32_t)f2bf(t0) | ((uint32_t)f2bf(t1) << 16);
  o[1] = (uint32_t)f2bf(t2) | ((uint32_t)f2bf(t3) << 16);
  o[2] = (uint32_t)f2bf(t4) | ((uint32_t)f2bf(t5) << 16);
  o[3] = (uint32_t)f2bf(t6) | ((uint32_t)f2bf(t7) << 16);
  return o;
}

// async global->LDS, 16B/lane; LDS dest is wave-uniform base.
DEVI void async_copy16(const void* g, void* l) {
  __attribute__((address_space(1))) void* gp =
      reinterpret_cast<__attribute__((address_space(1))) void*>(
          reinterpret_cast<uintptr_t>(const_cast<void*>(g)));
  __attribute__((address_space(3))) void* lp =
      reinterpret_cast<__attribute__((address_space(3))) void*>(
          static_cast<uint32_t>(reinterpret_cast<uintptr_t>(l)));
  __builtin_amdgcn_global_load_lds(gp, lp, 16, 0, 0);
}

// ---------- f32->bf16 conversion, weights+s5 only ----------
struct CvtSeg { const f32x4* src; u32x4* dst; };
struct CvtArgs { CvtSeg seg[5]; int start[6]; };

__global__ void cvt_multi(CvtArgs a, int total8) {
  int i = blockIdx.x * blockDim.x + threadIdx.x;
  const int stride = gridDim.x * blockDim.x;
  for (; i < total8; i += stride) {
    int s = 0;
#pragma unroll
    for (int j = 1; j < 5; ++j) s += (i >= a.start[j]);
    const int off = i - a.start[s];
    f32x4 f0 = a.seg[s].src[off * 2];
    f32x4 f1 = a.seg[s].src[off * 2 + 1];
    a.seg[s].dst[off] = cvt8(f0, f1);
  }
}

__global__ void zero_kernel(float* __restrict__ p) { p[threadIdx.x] = 0.0f; }

// ---------- GN coef: ga=gamma*rsqrt(var+eps), be=beta-mean*ga ----------
__global__ void gn_coef(const float* __restrict__ stats, const float* __restrict__ gamma,
                        const float* __restrict__ beta, float* __restrict__ ga,
                        float* __restrict__ be, int C, float invcnt) {
  int ch = blockIdx.x * blockDim.x + threadIdx.x;
  if (ch >= C) return;
  int g = ch / (C >> 5);
  float mean = stats[2 * g] * invcnt;
  float var = stats[2 * g + 1] * invcnt - mean * mean;
  float inv = rsqrtf(var + 1e-5f);
  float gm = gamma[ch] * inv;
  ga[ch] = gm;
  be[ch] = beta[ch] - mean * gm;
}

// ---------- 4-wave GEMM: BM=32*FM, BN=128, BK=64, 2 LDS buffers, 2-3 blocks/CU ----------
// C = A*B^T + bias. A row r = [ gather-part (dg cols, via up[]) | direct f32 feats ].
// GMODE 0: A is plain bf16, no gather (pass dg=K) -> global_load_lds.
// GMODE 1: gather part = bf16 via global_load_lds; direct part = f32 reg-staged->cvt8.
// GMODE 2: gather part = bf16 reg-staged + GN+LeakyReLU (gn8); direct = f32 reg-staged.
// EPI 0: bf16 out, 1: f32 out. STATS: fused per-group sum/sumsq of outputs.
// LDS swizzle (T2): 16B-chunk col ^= (row&7); applied on global source addr /
// reg ds_write position, un-applied on ds_read. Conflict-free (round-3: 0).
template <int FM, int GMODE, int EPI, int STATS>
__global__ __launch_bounds__(256, FM == 2 ? 3 : 2) void gemm4(
    const ushort* __restrict__ Ag, const float* __restrict__ Adf,
    const int* __restrict__ up, int dg,
    const float* __restrict__ gacoef, const float* __restrict__ becoef,
    const ushort* __restrict__ Bw, const float* __restrict__ bias,
    void* __restrict__ Cout, float* __restrict__ stats,
    int M, int N, int K) {
  constexpr int BM = 32 * FM, BN = 128, BK = 64;
  constexpr int ABY = BM * BK * 2;        // 4096*FM
  constexpr int BUF = ABY + BN * BK * 2;  // ABY + 16384
  __shared__ __align__(16) char smem[2 * BUF];
  __shared__ int s_up[BM];
  __shared__ float ssum[32], ssq[32];

  const int nbn = N >> 7;
  const int bm = (int)blockIdx.x / nbn;
  const int bn = (int)blockIdx.x % nbn;
  const int row0 = bm * BM, col0 = bn * BN;
  const int tid = threadIdx.x, lane = tid & 63, wave = tid >> 6;
  const int wm = wave >> 1, wn = wave & 1;
  const int dd = K - dg;
  const int ng = dg / BK;
  const int nt = K / BK;

  if constexpr (GMODE != 0) { if (tid < BM) s_up[tid] = up[row0 + tid]; }
  if constexpr (STATS) { if (tid < 32) { ssum[tid] = 0.f; ssq[tid] = 0.f; } }
  __syncthreads();  // also drains counters -> clean vmcnt baseline

  // per-thread staging geometry: FM A-chunks, 4 B-chunks of 16B
  int cs_[FM];
  const ushort* pG[FM]; const float* pD[FM];
#pragma unroll
  for (int li = 0; li < FM; ++li) {
    const int chunk = li * 256 + tid;
    const int r = chunk >> 3;
    cs_[li] = ((chunk & 7) ^ (r & 7)) << 3;
    if constexpr (GMODE == 0) {
      pG[li] = Ag + (size_t)(row0 + r) * K + cs_[li];
      pD[li] = nullptr;
    } else {
      pG[li] = Ag + (size_t)s_up[r] * dg + cs_[li];
      pD[li] = Adf + (size_t)(row0 + r) * dd + cs_[li];
    }
  }
  const ushort* pB[4];
#pragma unroll
  for (int li = 0; li < 4; ++li) {
    const int chunk = li * 256 + tid;
    const int rb = chunk >> 3;
    pB[li] = Bw + (size_t)(col0 + rb) * K + (((chunk & 7) ^ (rb & 7)) << 3);
  }

  u32x4 rgv[FM];        // gathered bf16 (GMODE2)
  f32x4 rdv[2 * FM];    // direct f32

  auto issueA = [&](int t2, char* buf) {
    const int k0 = t2 * BK;
    if (t2 < ng) {
      if constexpr (GMODE == 2) {
#pragma unroll
        for (int li = 0; li < FM; ++li) rgv[li] = *(const u32x4*)(pG[li] + k0);
      } else {
#pragma unroll
        for (int li = 0; li < FM; ++li)
          async_copy16(pG[li] + k0, buf + li * 4096 + wave * 1024);
      }
    } else {
      const int kd = k0 - dg;
#pragma unroll
      for (int li = 0; li < FM; ++li) {
        rdv[2 * li]     = *(const f32x4*)(pD[li] + kd);
        rdv[2 * li + 1] = *(const f32x4*)(pD[li] + kd + 4);
      }
    }
  };
  auto consumeA = [&](int t1, char* buf) {  // reg-staged tiles only
    const int k0 = t1 * BK;
    if (t1 < ng) {  // GMODE2 gather + GN
#pragma unroll
      for (int li = 0; li < FM; ++li) {
        f32x4 g0 = *(const f32x4*)(gacoef + k0 + cs_[li]);
        f32x4 g1 = *(const f32x4*)(gacoef + k0 + cs_[li] + 4);
        f32x4 b0 = *(const f32x4*)(becoef + k0 + cs_[li]);
        f32x4 b1 = *(const f32x4*)(becoef + k0 + cs_[li] + 4);
        *(u32x4*)(buf + li * 4096 + tid * 16) = gn8(rgv[li], g0, g1, b0, b1);
      }
    } else {
#pragma unroll
      for (int li = 0; li < FM; ++li)
        *(u32x4*)(buf + li * 4096 + tid * 16) = cvt8(rdv[2 * li], rdv[2 * li + 1]);
    }
  };
  auto issueB = [&](int t2, char* buf) {
#pragma unroll
    for (int li = 0; li < 4; ++li)
      async_copy16(pB[li] + t2 * BK, buf + ABY + li * 4096 + wave * 1024);
  };

  // ds_read fragment byte offsets (loop-invariant, swizzled)
  int offA[2][FM], offB[2][4];
#pragma unroll
  for (int kk = 0; kk < 2; ++kk) {
    const int ch = kk * 4 + (lane >> 4);
#pragma unroll
    for (int m = 0; m < FM; ++m) {
      const int ra = wm * 16 * FM + m * 16 + (lane & 15);
      offA[kk][m] = ra * 128 + ((ch ^ (ra & 7)) << 4);
    }
#pragma unroll
    for (int n = 0; n < 4; ++n) {
      const int rb = wn * 64 + n * 16 + (lane & 15);
      offB[kk][n] = ABY + rb * 128 + ((ch ^ (rb & 7)) << 4);
    }
  }

  // --- prologue: tile 0 fully staged ---
  issueA(0, smem);
  __builtin_amdgcn_sched_barrier(0);
  issueB(0, smem);
  WAITVM0;
  if constexpr (GMODE == 2) { consumeA(0, smem); }
  WAITLGKM;
  __builtin_amdgcn_sched_barrier(0);
  __builtin_amdgcn_s_barrier();

  f32x4 acc[FM][4] = {};
  for (int t = 0; t < nt; ++t) {
    char* cur = smem + (t & 1) * BUF;
    char* nxt = smem + ((t + 1) & 1) * BUF;
    const bool pf = (t + 1) < nt;
    if (pf) {
      issueA(t + 1, nxt);               // A first (consumed earliest)
      __builtin_amdgcn_sched_barrier(0);
      issueB(t + 1, nxt);               // 4 glds after
    }
#pragma unroll
    for (int kk = 0; kk < 2; ++kk) {
      bf16x8 af[FM], bv[4];
#pragma unroll
      for (int m = 0; m < FM; ++m) af[m] = *(const bf16x8*)(cur + offA[kk][m]);
#pragma unroll
      for (int n = 0; n < 4; ++n) bv[n] = *(const bf16x8*)(cur + offB[kk][n]);
      __builtin_amdgcn_s_setprio(1);
#pragma unroll
      for (int m = 0; m < FM; ++m)
#pragma unroll
        for (int n = 0; n < 4; ++n)
          acc[m][n] = __builtin_amdgcn_mfma_f32_16x16x32_bf16(af[m], bv[n], acc[m][n], 0, 0, 0);
      __builtin_amdgcn_s_setprio(0);
    }
    if (pf) {
      const bool reg1 = (GMODE == 2) || (GMODE == 1 && (t + 1) >= ng);
      if (reg1) {
        WAITVM4;                         // A reg-loads landed; 4 B-glds in flight
        consumeA(t + 1, nxt);
      }
    }
    WAITVM0;
    WAITLGKM;
    __builtin_amdgcn_sched_barrier(0);
    __builtin_amdgcn_s_barrier();
  }

  // --- epilogue: bias, store, optional fused group stats ---
  const int cr = (lane >> 4) << 2;
  const int cc = lane & 15;
  float sacc[4] = {0, 0, 0, 0}, qacc[4] = {0, 0, 0, 0};
#pragma unroll
  for (int n = 0; n < 4; ++n) {
    const int colg = col0 + wn * 64 + n * 16 + cc;
    const float bvv = bias[colg];
#pragma unroll
    for (int m = 0; m < FM; ++m) {
      const int rowg = row0 + wm * 16 * FM + m * 16 + cr;
#pragma unroll
      for (int r2 = 0; r2 < 4; ++r2) {
        const float v = acc[m][n][r2] + bvv;
        if constexpr (STATS) { sacc[n] += v; qacc[n] += v * v; }
        if constexpr (EPI == 0)
          ((ushort*)Cout)[(size_t)(rowg + r2) * N + colg] = f2bf(v);
        else
          ((float*)Cout)[(size_t)(rowg + r2) * N + colg] = v;
      }
    }
  }
  if constexpr (STATS) {
    const int gsize = N >> 5;
#pragma unroll
    for (int n = 0; n < 4; ++n) {
      float s = sacc[n], q = qacc[n];
      s += __shfl_xor(s, 16); q += __shfl_xor(q, 16);
      s += __shfl_xor(s, 32); q += __shfl_xor(q, 32);
      if (lane < 16) {
        const int colg = col0 + wn * 64 + n * 16 + lane;
        const int g = colg / gsize;
        atomicAdd(&ssum[g], s);
        atomicAdd(&ssq[g], q);
      }
    }
    __syncthreads();
    if (tid < 32) {
      const int g0 = col0 / gsize, g1 = (col0 + BN) / gsize;
      if (tid >= g0 && tid < g1) {
        atomicAdd(&stats[2 * tid], ssum[tid]);
        atomicAdd(&stats[2 * tid + 1], ssq[tid]);
      }
    }
  }
}

// ---------- host ----------
extern "C" void kernel_launch(void* const* d_in, const int* in_sizes, int n_in,
                              void* d_out, int out_size, void* d_ws, size_t ws_size,
                              hipStream_t stream) {
  const float* s2   = (const float*)d_in[0];   // (131072, 256)
  const float* s3   = (const float*)d_in[1];   // (32768, 512)
  const float* s4   = (const float*)d_in[2];   // (8192, 1024)
  const float* s5   = (const float*)d_in[3];   // (2048, 2048)
  const int*   up1  = (const int*)d_in[4];
  const int*   up2  = (const int*)d_in[5];
  const int*   up3  = (const int*)d_in[6];
  const float* W_in = (const float*)d_in[7];   // (2048, 2048)
  const float* b_in = (const float*)d_in[8];
  const float* W4   = (const float*)d_in[9];   // (1024, 3072)
  const float* b4   = (const float*)d_in[10];
  const float* g4   = (const float*)d_in[11];
  const float* bt4  = (const float*)d_in[12];
  const float* W3   = (const float*)d_in[13];  // (512, 1536)
  const float* b3   = (const float*)d_in[14];
  const float* g3   = (const float*)d_in[15];
  const float* bt3  = (const float*)d_in[16];
  const float* W2   = (const float*)d_in[17];  // (256, 768)
  const float* b2   = (const float*)d_in[18];
  float* out = (float*)d_out;
  char* ws = (char*)d_ws;

  // Workspace (~84 MB)
  ushort* s5b   = (ushort*)(ws + 0);
  ushort* Winb  = (ushort*)(ws + 8388608);
  ushort* x5b   = (ushort*)(ws + 16777216);
  ushort* W4b   = (ushort*)(ws + 25165824);
  ushort* W3b   = (ushort*)(ws + 31457280);
  ushort* W2b   = (ushort*)(ws + 33030144);
  float*  stats = (float*)(ws + 33423360);   // 128 f32
  float*  cga4  = (float*)(ws + 33423872);
  float*  cbe4  = (float*)(ws + 33427968);
  float*  cga3  = (float*)(ws + 33432064);
  float*  cbe3  = (float*)(ws + 33434112);
  ushort* l4lin = (ushort*)(ws + 33554432);  // 8192x1024
  ushort* l3lin = (ushort*)(ws + 50331648);  // 32768x512

  zero_kernel<<<1, 128, 0, stream>>>(stats);

  // convert weights + s5 only
  CvtArgs ca;
  const float* srcs[5] = { s5, W_in, W4, W3, W2 };
  ushort* dsts[5] = { s5b, Winb, W4b, W3b, W2b };
  long ns[5] = { 2048L*2048, 2048L*2048, 1024L*3072, 512L*1536, 256L*768 };
  int cum = 0;
  for (int i = 0; i < 5; ++i) {
    ca.seg[i].src = (const f32x4*)srcs[i];
    ca.seg[i].dst = (u32x4*)dsts[i];
    ca.start[i] = cum;
    cum += (int)(ns[i] >> 3);
  }
  ca.start[5] = cum;
  cvt_multi<<<2048, 256, 0, stream>>>(ca, cum);

  // x5 = s5 @ W_in^T + b_in (2048x2048, K=2048)  FM=2 -> BM=64, grid 32x16=512
  gemm4<2, 0, 0, 0><<<512, 256, 0, stream>>>(
      s5b, nullptr, nullptr, 2048, nullptr, nullptr, Winb, b_in,
      x5b, nullptr, 2048, 2048, 2048);
  // l4lin = concat(x5[up3], s4_f32) @ W4^T + b4, stats fused (8192x1024, K=3072) grid 64x8=512
  gemm4<4, 1, 0, 1><<<512, 256, 0, stream>>>(
      x5b, s4, up3, 2048, nullptr, nullptr, W4b, b4,
      l4lin, stats, 8192, 1024, 3072);
  gn_coef<<<4, 256, 0, stream>>>(stats, g4, bt4, cga4, cbe4, 1024, 1.0f / 262144.0f);
  // l3lin = concat(GN(l4lin)[up2], s3_f32) @ W3^T + b3, stats fused (32768x512, K=1536) grid 256x4=1024
  gemm4<4, 2, 0, 1><<<1024, 256, 0, stream>>>(
      l4lin, s3, up2, 1024, cga4, cbe4, W3b, b3,
      l3lin, stats + 64, 32768, 512, 1536);
  gn_coef<<<2, 256, 0, stream>>>(stats + 64, g3, bt3, cga3, cbe3, 512, 1.0f / 524288.0f);
  // out = concat(GN(l3lin)[up1], s2_f32) @ W2^T + b2 -> f32 (131072x256, K=768) grid 1024x2=2048
  gemm4<4, 2, 1, 0><<<2048, 256, 0, stream>>>(
      l3lin, s2, up1, 512, cga3, cbe3, W2b, b2,
      out, nullptr, 131072, 256, 768);

  (void)in_sizes; (void)n_in; (void)out_size; (void)ws_size;
}

// Round 6
// 358.703 us; speedup vs baseline: 1.4894x; 1.1257x over previous
//
#include <hip/hip_runtime.h>
#include <cstdint>
#include <cstddef>

#define DEVI __device__ __forceinline__
#define WAITVM0 asm volatile("s_waitcnt vmcnt(0)" ::: "memory")
#define WAITLGKM asm volatile("s_waitcnt lgkmcnt(0)" ::: "memory")

typedef __bf16 bf16x8 __attribute__((ext_vector_type(8)));
typedef float f32x4 __attribute__((ext_vector_type(4)));
typedef uint32_t u32x4 __attribute__((ext_vector_type(4)));

// ---------- scalar helpers ----------
DEVI ushort f2bf(float f) {
  union { float f; uint32_t u; } v; v.f = f;
  uint32_t u = v.u;
  return (ushort)((u + 0x7FFFu + ((u >> 16) & 1u)) >> 16);  // RNE
}
DEVI float bf2f(ushort h) {
  union { uint32_t u; float f; } v; v.u = ((uint32_t)h) << 16;
  return v.f;
}
DEVI float lrelu(float t) { return t > 0.0f ? t : 0.1f * t; }

DEVI u32x4 cvt8(f32x4 a, f32x4 b) {  // 8 f32 -> 8 packed bf16
  u32x4 o;
  o[0] = (uint32_t)f2bf(a[0]) | ((uint32_t)f2bf(a[1]) << 16);
  o[1] = (uint32_t)f2bf(a[2]) | ((uint32_t)f2bf(a[3]) << 16);
  o[2] = (uint32_t)f2bf(b[0]) | ((uint32_t)f2bf(b[1]) << 16);
  o[3] = (uint32_t)f2bf(b[2]) | ((uint32_t)f2bf(b[3]) << 16);
  return o;
}
// GN+LeakyReLU on 8 packed bf16 with per-channel f32 coefs
DEVI u32x4 gn8(u32x4 d, f32x4 g0, f32x4 g1, f32x4 b0, f32x4 b1) {
  float f0 = bf2f((ushort)(d[0] & 0xffffu)), f1 = bf2f((ushort)(d[0] >> 16));
  float f2 = bf2f((ushort)(d[1] & 0xffffu)), f3 = bf2f((ushort)(d[1] >> 16));
  float f4 = bf2f((ushort)(d[2] & 0xffffu)), f5 = bf2f((ushort)(d[2] >> 16));
  float f6 = bf2f((ushort)(d[3] & 0xffffu)), f7 = bf2f((ushort)(d[3] >> 16));
  float t0 = lrelu(f0 * g0[0] + b0[0]), t1 = lrelu(f1 * g0[1] + b0[1]);
  float t2 = lrelu(f2 * g0[2] + b0[2]), t3 = lrelu(f3 * g0[3] + b0[3]);
  float t4 = lrelu(f4 * g1[0] + b1[0]), t5 = lrelu(f5 * g1[1] + b1[1]);
  float t6 = lrelu(f6 * g1[2] + b1[2]), t7 = lrelu(f7 * g1[3] + b1[3]);
  u32x4 o;
  o[0] = (uint32_t)f2bf(t0) | ((uint32_t)f2bf(t1) << 16);
  o[1] = (uint32_t)f2bf(t2) | ((uint32_t)f2bf(t3) << 16);
  o[2] = (uint32_t)f2bf(t4) | ((uint32_t)f2bf(t5) << 16);
  o[3] = (uint32_t)f2bf(t6) | ((uint32_t)f2bf(t7) << 16);
  return o;
}

// async global->LDS, 16B/lane; LDS dest is wave-uniform base.
DEVI void async_copy16(const void* g, void* l) {
  __attribute__((address_space(1))) void* gp =
      reinterpret_cast<__attribute__((address_space(1))) void*>(
          reinterpret_cast<uintptr_t>(const_cast<void*>(g)));
  __attribute__((address_space(3))) void* lp =
      reinterpret_cast<__attribute__((address_space(3))) void*>(
          static_cast<uint32_t>(reinterpret_cast<uintptr_t>(l)));
  __builtin_amdgcn_global_load_lds(gp, lp, 16, 0, 0);
}

// ---------- f32->bf16 conversion, WEIGHTS only (4 segments) ----------
struct CvtSeg { const f32x4* src; u32x4* dst; };
struct CvtArgs { CvtSeg seg[4]; int start[5]; };

__global__ void cvt_multi(CvtArgs a, int total8) {
  int i = blockIdx.x * blockDim.x + threadIdx.x;
  const int stride = gridDim.x * blockDim.x;
  for (; i < total8; i += stride) {
    int s = 0;
#pragma unroll
    for (int j = 1; j < 4; ++j) s += (i >= a.start[j]);
    const int off = i - a.start[s];
    f32x4 f0 = a.seg[s].src[off * 2];
    f32x4 f1 = a.seg[s].src[off * 2 + 1];
    a.seg[s].dst[off] = cvt8(f0, f1);
  }
}

__global__ void zero_kernel(float* __restrict__ p) { p[threadIdx.x] = 0.0f; }

// ---------- GN coef: ga=gamma*rsqrt(var+eps), be=beta-mean*ga ----------
__global__ void gn_coef(const float* __restrict__ stats, const float* __restrict__ gamma,
                        const float* __restrict__ beta, float* __restrict__ ga,
                        float* __restrict__ be, int C, float invcnt) {
  int ch = blockIdx.x * blockDim.x + threadIdx.x;
  if (ch >= C) return;
  int g = ch / (C >> 5);
  float mean = stats[2 * g] * invcnt;
  float var = stats[2 * g + 1] * invcnt - mean * mean;
  float inv = rsqrtf(var + 1e-5f);
  float gm = gamma[ch] * inv;
  ga[ch] = gm;
  be[ch] = beta[ch] - mean * gm;
}

// ---------- standalone GN+LeakyReLU apply: y = lrelu(x*ga+be), bf16->bf16 ----------
// Each thread owns a fixed 8-channel column slice (coefs in regs), strides rows.
__global__ void gn_apply(const ushort* __restrict__ x, const float* __restrict__ ga,
                         const float* __restrict__ be, ushort* __restrict__ y,
                         int Nrows, int C) {
  const int tpr = C >> 3;  // threads per row
  const int gtid = blockIdx.x * blockDim.x + threadIdx.x;
  const int c8 = (gtid % tpr) * 8;
  const f32x4 g0 = *(const f32x4*)(ga + c8), g1 = *(const f32x4*)(ga + c8 + 4);
  const f32x4 b0 = *(const f32x4*)(be + c8), b1 = *(const f32x4*)(be + c8 + 4);
  const int rstep = (gridDim.x * blockDim.x) / tpr;
  for (int r = gtid / tpr; r < Nrows; r += rstep) {
    u32x4 d = *(const u32x4*)(x + (size_t)r * C + c8);
    *(u32x4*)(y + (size_t)r * C + c8) = gn8(d, g0, g1, b0, b1);
  }
}

// ---------- 4-wave GEMM: BM=32*FM, BN=128, BK=64, 2 LDS buffers ----------
// C = A*B^T + bias. A row r = [ bf16 gather rows Ag[up[r]] (dg cols, pure
// global_load_lds DMA) | direct f32 feats row r (reg-staged + cvt8) ].
// ng = dg/64 gather tiles; x5 uses ng=0 (all-direct). EPI 0: bf16 out, 1: f32.
// STATS: fused per-group sum/sumsq of f32 outputs (for next layer's GN).
// T2 swizzle: 16B-chunk col ^= (row&7) on the global source / reg ds_write
// position, un-applied on ds_read (round-3: conflicts == 0, verified).
// XCD-bijective block swizzle: consecutive remapped bids share the A-row panel.
template <int FM, int EPI, int STATS>
__global__ __launch_bounds__(256, FM == 2 ? 3 : 2) void gemmx(
    const ushort* __restrict__ Ag, const float* __restrict__ Adf,
    const int* __restrict__ up, int dg,
    const ushort* __restrict__ Bw, const float* __restrict__ bias,
    void* __restrict__ Cout, float* __restrict__ stats,
    int M, int N, int K) {
  constexpr int BM = 32 * FM, BN = 128, BK = 64;
  constexpr int ABY = BM * BK * 2;        // 4096*FM
  constexpr int BUF = ABY + BN * BK * 2;  // ABY + 16384
  __shared__ __align__(16) char smem[2 * BUF];
  __shared__ int s_up[BM];
  __shared__ float ssum[32], ssq[32];

  const int nbn = N >> 7;
  // XCD swizzle: grid is always a multiple of 8
  const int cpx = (int)gridDim.x >> 3;
  const int bid = ((int)blockIdx.x & 7) * cpx + ((int)blockIdx.x >> 3);
  const int bm = bid / nbn, bn = bid % nbn;
  const int row0 = bm * BM, col0 = bn * BN;
  const int tid = threadIdx.x, lane = tid & 63, wave = tid >> 6;
  const int wm = wave >> 1, wn = wave & 1;
  const int dd = K - dg;
  const int ng = dg / BK;
  const int nt = K / BK;

  if (up != nullptr && tid < BM) s_up[tid] = up[row0 + tid];
  if constexpr (STATS) { if (tid < 32) { ssum[tid] = 0.f; ssq[tid] = 0.f; } }
  __syncthreads();  // also drains counters -> clean vmcnt baseline

  // per-thread staging geometry: FM A-chunks, 4 B-chunks of 16B each
  int cs_[FM];
  const ushort* pG[FM]; const float* pD[FM];
#pragma unroll
  for (int li = 0; li < FM; ++li) {
    const int chunk = li * 256 + tid;
    const int r = chunk >> 3;
    cs_[li] = ((chunk & 7) ^ (r & 7)) << 3;
    pG[li] = (ng > 0) ? (Ag + (size_t)s_up[r] * dg + cs_[li]) : nullptr;
    pD[li] = (ng < nt) ? (Adf + (size_t)(row0 + r) * dd + cs_[li]) : nullptr;
  }
  const ushort* pB[4];
#pragma unroll
  for (int li = 0; li < 4; ++li) {
    const int chunk = li * 256 + tid;
    const int rb = chunk >> 3;
    pB[li] = Bw + (size_t)(col0 + rb) * K + (((chunk & 7) ^ (rb & 7)) << 3);
  }

  f32x4 rdv[2 * FM];  // direct-f32 staging regs (single set, consumed same iter)

  auto issueA = [&](int t, char* buf) {
    const int k0 = t * BK;
    if (t < ng) {
#pragma unroll
      for (int li = 0; li < FM; ++li)
        async_copy16(pG[li] + k0, buf + li * 4096 + wave * 1024);
    } else {
      const int kd = k0 - dg;
#pragma unroll
      for (int li = 0; li < FM; ++li) {
        rdv[2 * li]     = *(const f32x4*)(pD[li] + kd);
        rdv[2 * li + 1] = *(const f32x4*)(pD[li] + kd + 4);
      }
    }
  };
  auto consumeD = [&](char* buf) {
#pragma unroll
    for (int li = 0; li < FM; ++li)
      *(u32x4*)(buf + li * 4096 + tid * 16) = cvt8(rdv[2 * li], rdv[2 * li + 1]);
  };
  auto issueB = [&](int t, char* buf) {
#pragma unroll
    for (int li = 0; li < 4; ++li)
      async_copy16(pB[li] + t * BK, buf + ABY + li * 4096 + wave * 1024);
  };

  // ds_read fragment byte offsets (loop-invariant, swizzled)
  int offA[2][FM], offB[2][4];
#pragma unroll
  for (int kk = 0; kk < 2; ++kk) {
    const int ch = kk * 4 + (lane >> 4);
#pragma unroll
    for (int m = 0; m < FM; ++m) {
      const int ra = wm * 16 * FM + m * 16 + (lane & 15);
      offA[kk][m] = ra * 128 + ((ch ^ (ra & 7)) << 4);
    }
#pragma unroll
    for (int n = 0; n < 4; ++n) {
      const int rb = wn * 64 + n * 16 + (lane & 15);
      offB[kk][n] = ABY + rb * 128 + ((ch ^ (rb & 7)) << 4);
    }
  }

  // --- prologue: tile 0 fully staged ---
  issueA(0, smem);
  __builtin_amdgcn_sched_barrier(0);
  issueB(0, smem);
  WAITVM0;
  if (ng == 0) consumeD(smem);
  WAITLGKM;
  __builtin_amdgcn_sched_barrier(0);
  __builtin_amdgcn_s_barrier();

  f32x4 acc[FM][4] = {};
  for (int t = 0; t < nt; ++t) {
    char* cur = smem + (t & 1) * BUF;
    char* nxt = smem + ((t + 1) & 1) * BUF;
    const bool pf = (t + 1) < nt;
    if (pf) {
      issueA(t + 1, nxt);
      __builtin_amdgcn_sched_barrier(0);
      issueB(t + 1, nxt);
    }
#pragma unroll
    for (int kk = 0; kk < 2; ++kk) {
      bf16x8 af[FM], bv[4];
#pragma unroll
      for (int m = 0; m < FM; ++m) af[m] = *(const bf16x8*)(cur + offA[kk][m]);
#pragma unroll
      for (int n = 0; n < 4; ++n) bv[n] = *(const bf16x8*)(cur + offB[kk][n]);
      __builtin_amdgcn_s_setprio(1);
#pragma unroll
      for (int m = 0; m < FM; ++m)
#pragma unroll
        for (int n = 0; n < 4; ++n)
          acc[m][n] = __builtin_amdgcn_mfma_f32_16x16x32_bf16(af[m], bv[n], acc[m][n], 0, 0, 0);
      __builtin_amdgcn_s_setprio(0);
    }
    WAITVM0;
    if (pf && (t + 1) >= ng) consumeD(nxt);
    WAITLGKM;
    __builtin_amdgcn_sched_barrier(0);
    __builtin_amdgcn_s_barrier();
  }

  // --- epilogue: bias, store, optional fused group stats ---
  const int cr = (lane >> 4) << 2;
  const int cc = lane & 15;
  float sacc[4] = {0, 0, 0, 0}, qacc[4] = {0, 0, 0, 0};
#pragma unroll
  for (int n = 0; n < 4; ++n) {
    const int colg = col0 + wn * 64 + n * 16 + cc;
    const float bvv = bias[colg];
#pragma unroll
    for (int m = 0; m < FM; ++m) {
      const int rowg = row0 + wm * 16 * FM + m * 16 + cr;
#pragma unroll
      for (int r2 = 0; r2 < 4; ++r2) {
        const float v = acc[m][n][r2] + bvv;
        if constexpr (STATS) { sacc[n] += v; qacc[n] += v * v; }
        if constexpr (EPI == 0)
          ((ushort*)Cout)[(size_t)(rowg + r2) * N + colg] = f2bf(v);
        else
          ((float*)Cout)[(size_t)(rowg + r2) * N + colg] = v;
      }
    }
  }
  if constexpr (STATS) {
    const int gsize = N >> 5;
#pragma unroll
    for (int n = 0; n < 4; ++n) {
      float s = sacc[n], q = qacc[n];
      s += __shfl_xor(s, 16); q += __shfl_xor(q, 16);
      s += __shfl_xor(s, 32); q += __shfl_xor(q, 32);
      if (lane < 16) {
        const int colg = col0 + wn * 64 + n * 16 + lane;
        const int g = colg / gsize;
        atomicAdd(&ssum[g], s);
        atomicAdd(&ssq[g], q);
      }
    }
    __syncthreads();
    if (tid < 32) {
      const int g0 = col0 / gsize, g1 = (col0 + BN) / gsize;
      if (tid >= g0 && tid < g1) {
        atomicAdd(&stats[2 * tid], ssum[tid]);
        atomicAdd(&stats[2 * tid + 1], ssq[tid]);
      }
    }
  }
}

// ---------- host ----------
extern "C" void kernel_launch(void* const* d_in, const int* in_sizes, int n_in,
                              void* d_out, int out_size, void* d_ws, size_t ws_size,
                              hipStream_t stream) {
  const float* s2   = (const float*)d_in[0];   // (131072, 256)
  const float* s3   = (const float*)d_in[1];   // (32768, 512)
  const float* s4   = (const float*)d_in[2];   // (8192, 1024)
  const float* s5   = (const float*)d_in[3];   // (2048, 2048)
  const int*   up1  = (const int*)d_in[4];
  const int*   up2  = (const int*)d_in[5];
  const int*   up3  = (const int*)d_in[6];
  const float* W_in = (const float*)d_in[7];   // (2048, 2048)
  const float* b_in = (const float*)d_in[8];
  const float* W4   = (const float*)d_in[9];   // (1024, 3072)
  const float* b4   = (const float*)d_in[10];
  const float* g4   = (const float*)d_in[11];
  const float* bt4  = (const float*)d_in[12];
  const float* W3   = (const float*)d_in[13];  // (512, 1536)
  const float* b3   = (const float*)d_in[14];
  const float* g3   = (const float*)d_in[15];
  const float* bt3  = (const float*)d_in[16];
  const float* W2   = (const float*)d_in[17];  // (256, 768)
  const float* b2   = (const float*)d_in[18];
  float* out = (float*)d_out;
  char* ws = (char*)d_ws;

  // Workspace layout (~120 MB, no overlays needed)
  ushort* Winb  = (ushort*)(ws + 0);          //  8.39 MB
  ushort* W4b   = (ushort*)(ws + 8388608);    //  6.29 MB
  ushort* W3b   = (ushort*)(ws + 14680064);   //  1.57 MB
  ushort* W2b   = (ushort*)(ws + 16252928);   //  0.39 MB
  float*  stats = (float*)(ws + 16646144);    //  512 B
  float*  cga4  = (float*)(ws + 16646656);
  float*  cbe4  = (float*)(ws + 16650752);
  float*  cga3  = (float*)(ws + 16654848);
  float*  cbe3  = (float*)(ws + 16656896);
  ushort* x5b   = (ushort*)(ws + 16777216);   //  8.39 MB (2048x2048)
  ushort* l4lin = (ushort*)(ws + 25165824);   // 16.78 MB (8192x1024)
  ushort* l4b   = (ushort*)(ws + 41943040);   // 16.78 MB
  ushort* l3lin = (ushort*)(ws + 58720256);   // 33.55 MB (32768x512)
  ushort* l3b   = (ushort*)(ws + 92274688);   // 33.55 MB

  zero_kernel<<<1, 128, 0, stream>>>(stats);

  // convert weights only
  CvtArgs ca;
  const float* srcs[4] = { W_in, W4, W3, W2 };
  ushort* dsts[4] = { Winb, W4b, W3b, W2b };
  long ns[4] = { 2048L*2048, 1024L*3072, 512L*1536, 256L*768 };
  int cum = 0;
  for (int i = 0; i < 4; ++i) {
    ca.seg[i].src = (const f32x4*)srcs[i];
    ca.seg[i].dst = (u32x4*)dsts[i];
    ca.start[i] = cum;
    cum += (int)(ns[i] >> 3);
  }
  ca.start[4] = cum;
  cvt_multi<<<1024, 256, 0, stream>>>(ca, cum);

  // x5 = s5(f32 direct) @ W_in^T + b_in (2048x2048, K=2048)  FM=2, grid 32x16=512
  gemmx<2, 0, 0><<<512, 256, 0, stream>>>(
      nullptr, s5, nullptr, 0, Winb, b_in, x5b, nullptr, 2048, 2048, 2048);
  // l4lin = concat(x5b[up3] DMA, s4 f32) @ W4^T + b4, stats fused (8192x1024,K=3072) grid 64x8=512
  gemmx<4, 0, 1><<<512, 256, 0, stream>>>(
      x5b, s4, up3, 2048, W4b, b4, l4lin, stats, 8192, 1024, 3072);
  gn_coef<<<4, 256, 0, stream>>>(stats, g4, bt4, cga4, cbe4, 1024, 1.0f / 262144.0f);
  gn_apply<<<2048, 256, 0, stream>>>(l4lin, cga4, cbe4, l4b, 8192, 1024);
  // l3lin = concat(l4b[up2] DMA, s3 f32) @ W3^T + b3, stats fused (32768x512,K=1536) grid 256x4=1024
  gemmx<4, 0, 1><<<1024, 256, 0, stream>>>(
      l4b, s3, up2, 1024, W3b, b3, l3lin, stats + 64, 32768, 512, 1536);
  gn_coef<<<2, 256, 0, stream>>>(stats + 64, g3, bt3, cga3, cbe3, 512, 1.0f / 524288.0f);
  gn_apply<<<2048, 256, 0, stream>>>(l3lin, cga3, cbe3, l3b, 32768, 512);
  // out = concat(l3b[up1] DMA, s2 f32) @ W2^T + b2 -> f32 (131072x256,K=768) grid 1024x2=2048
  gemmx<4, 1, 0><<<2048, 256, 0, stream>>>(
      l3b, s2, up1, 512, W2b, b2, out, nullptr, 131072, 256, 768);

  (void)in_sizes; (void)n_in; (void)out_size; (void)ws_size;
}